// Round 7
// baseline (359.121 us; speedup 1.0000x reference)
//
#include <hip/hip_runtime.h>
#include <hip/hip_bf16.h>
#include <math.h>

#define DIN 20
#define C 128
#define HC 256
#define EB1 8192
#define EB2 1024
#define MAXNB 400

typedef unsigned short u16;
typedef unsigned int u32;
typedef unsigned long long u64;
typedef __bf16 bf16x8 __attribute__((ext_vector_type(8)));
typedef float f32x4 __attribute__((ext_vector_type(4)));

__device__ __forceinline__ float bfbits2f(unsigned int lo16) {
    return __uint_as_float(lo16 << 16);
}
__device__ __forceinline__ u16 f2bf_rne(float f) {
    unsigned int b = __float_as_uint(f);
    return (u16)((b + 0x7FFFu + ((b >> 16) & 1u)) >> 16);
}

// exclusive scan of cnt[0..511] -> off[0..511]; wave-shuffle scan, 2 barriers
__device__ __forceinline__ void scan512f(u32* cnt, u32* off, u32* wsum4) {
    int t = threadIdx.x;
    int l = t & 63, w = t >> 6;
    u32 a = cnt[2 * t], b = cnt[2 * t + 1];
    u32 s = a + b;
    u32 isc = s;
    #pragma unroll
    for (int o = 1; o < 64; o <<= 1) {
        u32 n = __shfl_up(isc, o);
        if (l >= o) isc += n;
    }
    if (l == 63) wsum4[w] = isc;
    __syncthreads();
    u32 pre = 0;
    if (w > 0) pre += wsum4[0];
    if (w > 1) pre += wsum4[1];
    if (w > 2) pre += wsum4[2];
    u32 excl = pre + isc - s;
    off[2 * t] = excl;
    off[2 * t + 1] = excl + a;
    __syncthreads();
}

__device__ __forceinline__ void edge_at(int i, const int* s1, const int* d1,
    const int* s2, const int* d2, int E1, int T1, int E2, int NR,
    int& s, int& key)
{
    if (i < T1) {
        if (i < E1) { s = s1[i]; key = d1[i]; }
        else        { s = i - E1; key = i - E1; }
    } else {
        int k = i - T1;
        if (k < E2) { s = s2[k]; key = NR + d2[k]; }
        else        { s = k - E2; key = NR + (k - E2); }
    }
}

// ---------------- K_init: BN stats + dst-only bucket histogram + B-pack -----------
__global__ __launch_bounds__(256) void k_init(const float* __restrict__ x, int NR,
    float* __restrict__ stats, int SB, int AB,
    const int* __restrict__ dst1, const int* __restrict__ dst2,
    int E1, int L1, int E2, int L2, int NB, u32* __restrict__ bucketCnt,
    const float* __restrict__ g2_ws, u16* __restrict__ wsp)
{
    __shared__ float L[256][DIN];
    __shared__ u32 cnt[MAXNB];
    int t = threadIdx.x;
    int bid = blockIdx.x;
    if (bid < SB) {
        int r = bid * 256 + t;
        if (r < NR) {
            #pragma unroll
            for (int k = 0; k < DIN; k++) L[t][k] = x[r * DIN + k];
        } else {
            #pragma unroll
            for (int k = 0; k < DIN; k++) L[t][k] = 0.f;
        }
        __syncthreads();
        if (t < 210) {
            int p = 0, q = t;
            while (q >= DIN - p) { q -= (DIN - p); p++; }
            q += p;
            float acc = 0.f;
            for (int rr = 0; rr < 256; rr++) acc += L[rr][p] * L[rr][q];
            atomicAdd(&stats[p * DIN + q], acc);
            if (p != q) atomicAdd(&stats[q * DIN + p], acc);
        } else if (t < 230) {
            int k = t - 210;
            float acc = 0.f;
            for (int rr = 0; rr < 256; rr++) acc += L[rr][k];
            atomicAdd(&stats[400 + k], acc);
        }
        return;
    }
    if (bid < SB + AB) {
        // dst-only bucket histogram
        for (int i = t; i < NB; i += 256) cnt[i] = 0;
        __syncthreads();
        int T1 = E1 + L1, T = T1 + E2 + L2;
        int base = (bid - SB) * EB1;
        int nE = T - base; if (nE > EB1) nE = EB1;
        for (int j = t; j < nE; j += 256) {
            int i = base + j, key;
            if (i < T1) key = (i < E1) ? dst1[i] : (i - E1);
            else { int k = i - T1; key = NR + ((k < E2) ? dst2[k] : (k - E2)); }
            atomicAdd(&cnt[key >> 9], 1u);
        }
        __syncthreads();
        for (int b = t; b < NB; b += 256) {
            u32 c = cnt[b];
            if (c) atomicAdd(&bucketCnt[b], c);
        }
        return;
    }
    // ---- B-pack role (32 blocks) ----
    int idx0 = ((bid - SB - AB) * 256 + t) * 4;
    #pragma unroll
    for (int i = 0; i < 4; i++) {
        int flat = idx0 + i;           // [nt(16)][kb(4)][lane(64)][j(8)]
        int j = flat & 7;
        int lane = (flat >> 3) & 63;
        int kb = (flat >> 9) & 3;
        int nt = flat >> 11;
        int k = kb * 32 + (lane >> 4) * 8 + j;
        int n = nt * 16 + (lane & 15);
        wsp[flat] = f2bf_rne(g2_ws[k * HC + n]);
    }
}

// ---------------- K_scanpre: precomp (block 0) + bucket scan (block 1) ------------
__global__ __launch_bounds__(256) void k_scanpre(float* __restrict__ stats,
    const float* __restrict__ W,
    const float* __restrict__ gamma, const float* __restrict__ beta,
    const float* __restrict__ g1_wd, const float* __restrict__ g1_ad,
    const float* __restrict__ g2_wd, const float* __restrict__ g2_ad,
    const float* __restrict__ g1_ws, const float* __restrict__ g1_as,
    const float* __restrict__ g2_ws, const float* __restrict__ g2_as,
    const float* __restrict__ g1b, float invN,
    const u32* __restrict__ bucketCnt, int NB, int n2,
    u32* __restrict__ bucketBase, u32* __restrict__ gcur, int* __restrict__ off)
{
    int t = threadIdx.x;
    if (blockIdx.x == 1) {
        __shared__ u32 cnt[512], offL[512], wsum4[4];
        for (int i = t; i < 512; i += 256) cnt[i] = (i < NB) ? bucketCnt[i] : 0u;
        __syncthreads();
        scan512f(cnt, offL, wsum4);
        for (int i = t; i < NB; i += 256) {
            u32 v = offL[i];
            bucketBase[i] = v;
            gcur[i] = v;
        }
        if (t == 0) {
            u32 total = offL[511] + cnt[511];
            bucketBase[NB] = total;
            off[n2] = (int)total;
        }
        return;
    }
    __shared__ float Sm[420];
    __shared__ float Wm[DIN * C];
    __shared__ float vd1s[256];
    __shared__ float vd2s[256];
    __shared__ float sS[128];
    __shared__ float sSh[128];
    for (int i = t; i < 420; i += 256) Sm[i] = stats[i];
    for (int i = t; i < DIN * C; i += 256) Wm[i] = W[i];
    __syncthreads();
    if (t < C) {
        float w[DIN];
        #pragma unroll
        for (int k = 0; k < DIN; k++) w[k] = Wm[k * C + t];
        float mb = 0.f;
        #pragma unroll
        for (int k = 0; k < DIN; k++) mb += Sm[400 + k] * invN * w[k];
        float e2 = 0.f;
        for (int p = 0; p < DIN; p++) {
            float acc2 = 0.f;
            #pragma unroll
            for (int q = 0; q < DIN; q++) acc2 += Sm[p * DIN + q] * w[q];
            e2 += w[p] * acc2;
        }
        e2 *= invN;
        float var = e2 - mb * mb;
        float s = gamma[t] * rsqrtf(var + 1e-5f);
        float sh = beta[t] - s * mb;   // b_rl cancels inside BN
        stats[420 + t] = s;
        stats[548 + t] = sh;
        sS[t] = s;
        sSh[t] = sh;
    }
    {
        int k = t >> 1, h = t & 1;
        const float4* wd1 = (const float4*)(g1_wd + k * HC + h * C);
        const float4* wd2 = (const float4*)(g2_wd + k * HC + h * C);
        const float4* ws1 = (const float4*)(g1_ws + k * HC + h * C);
        const float4* ws2 = (const float4*)(g2_ws + k * HC + h * C);
        const float4* ad1 = (const float4*)(g1_ad + h * C);
        const float4* ad2 = (const float4*)(g2_ad + h * C);
        const float4* as1 = (const float4*)(g1_as + h * C);
        const float4* as2 = (const float4*)(g2_as + h * C);
        float a1 = 0.f, a2 = 0.f, s1 = 0.f, s2 = 0.f;
        #pragma unroll 4
        for (int q = 0; q < 32; q++) {
            float4 x, y;
            x = wd1[q]; y = ad1[q];
            a1 += x.x * y.x + x.y * y.y + x.z * y.z + x.w * y.w;
            x = wd2[q]; y = ad2[q];
            a2 += x.x * y.x + x.y * y.y + x.z * y.z + x.w * y.w;
            x = ws1[q]; y = as1[q];
            s1 += x.x * y.x + x.y * y.y + x.z * y.z + x.w * y.w;
            x = ws2[q]; y = as2[q];
            s2 += x.x * y.x + x.y * y.y + x.z * y.z + x.w * y.w;
        }
        stats[676 + t] = a1;
        stats[932 + t] = a2;
        stats[1200 + t] = s1;
        stats[1456 + t] = s2;
        vd1s[t] = a1;
        vd2s[t] = a2;
    }
    __syncthreads();
    {
        int k = t >> 1, h = t & 1;
        const float4* ws1p = (const float4*)(g1_ws + k * HC + h * C);
        float t0 = 0.f, t1 = 0.f;
        #pragma unroll 4
        for (int q = 0; q < 32; q++) {
            float4 wv = ws1p[q];
            int c = q * 4;
            t0 += wv.x * vd2s[(c + 0) * 2 + 0] + wv.y * vd2s[(c + 1) * 2 + 0]
                + wv.z * vd2s[(c + 2) * 2 + 0] + wv.w * vd2s[(c + 3) * 2 + 0];
            t1 += wv.x * vd2s[(c + 0) * 2 + 1] + wv.y * vd2s[(c + 1) * 2 + 1]
                + wv.z * vd2s[(c + 2) * 2 + 1] + wv.w * vd2s[(c + 3) * 2 + 1];
        }
        stats[1712 + t * 2 + 0] = t0;
        stats[1712 + t * 2 + 1] = t1;
    }
    if (t < 2) {
        float cb = 0.f;
        for (int k = 0; k < C; k++) cb += g1b[k] * vd2s[k * 2 + t];
        stats[1188 + t] = cb;
    }
    if (t < 80) {
        int k = t >> 2, h4 = t & 3, h = h4 & 1;
        const float* vs = (h4 < 2) ? vd1s : vd2s;
        float acc = 0.f;
        for (int c = 0; c < C; c++) acc += sS[c] * Wm[k * C + c] * vs[c * 2 + h];
        stats[2240 + t] = acc;
    } else if (t < 84) {
        int h4 = t - 80, h = h4 & 1;
        const float* vs = (h4 < 2) ? vd1s : vd2s;
        float acc = 0.f;
        for (int c = 0; c < C; c++) acc += sSh[c] * vs[c * 2 + h];
        stats[2320 + h4] = acc;
    }
}

// ---------------- K_mid: kA2 counting-sort ∥ r0f GEMV ∥ ingredient psi ------------
// blocks [0,A2B): kA2 (EB2=1024); [A2B,+R0B): r0f; [A2B+R0B,+IB): ing
__global__ __launch_bounds__(256) void k_mid(
    const int* __restrict__ src1, const int* __restrict__ dst1,
    const int* __restrict__ src2, const int* __restrict__ dst2,
    int E1, int L1, int E2, int L2, int NR, int NB,
    u32* __restrict__ gcur, u64* __restrict__ pairs, int A2B, int R0B,
    const float* __restrict__ x, const float* __restrict__ stats,
    float* __restrict__ a_d, float* __restrict__ advd,
    const float* __restrict__ ing_table, const int* __restrict__ ing_ids, int NI,
    float* __restrict__ a_si, float* __restrict__ psi)
{
    __shared__ __align__(16) char sm[24144];
    int t = threadIdx.x;
    int bid = blockIdx.x;
    if (bid < A2B) {
        u64* ldsE = (u64*)sm;                    // 1024 * 8 = 8192
        u64* ldsS = ldsE + EB2;                  // 8192
        u32* cntA = (u32*)(ldsS + EB2);          // 2048
        u32* cntB = cntA + 512;                  // 2048
        u32* offL = cntB + 512;                  // 2048
        u32* wsum4 = offL + 512;                 // 16
        u32* gbase = wsum4 + 4;                  // 1600
        for (int i = t; i < 512; i += 256) { cntA[i] = 0; cntB[i] = 0; }
        __syncthreads();
        int T1 = E1 + L1, T = T1 + E2 + L2;
        int base = bid * EB2;
        int nE = T - base; if (nE > EB2) nE = EB2;
        for (int j = t; j < nE; j += 256) {
            int s, key;
            edge_at(base + j, src1, dst1, src2, dst2, E1, T1, E2, NR, s, key);
            ldsE[j] = ((u64)(u32)key << 32) | (u32)s;
            atomicAdd(&cntA[key >> 9], 1u);
        }
        __syncthreads();
        scan512f(cntA, offL, wsum4);
        for (int b = t; b < NB; b += 256) {
            u32 c = cntA[b];
            gbase[b] = c ? atomicAdd(&gcur[b], c) : 0u;
        }
        __syncthreads();
        for (int j = t; j < nE; j += 256) {
            u64 e = ldsE[j];
            u32 b = ((u32)(e >> 32)) >> 9;
            u32 r = atomicAdd(&cntB[b], 1u);
            ldsS[offL[b] + r] = e;
        }
        __syncthreads();
        for (int j = t; j < nE; j += 256) {
            u64 e = ldsS[j];
            u32 b = ((u32)(e >> 32)) >> 9;
            pairs[gbase[b] + ((u32)j - offL[b])] = e;
        }
        return;
    }
    if (bid < A2B + R0B) {
        float* fv = (float*)sm;
        if (t < 84) fv[t] = stats[2240 + t];
        __syncthreads();
        int r = (bid - A2B) * 256 + t;
        if (r < NR) {
            const float4* xp = (const float4*)(x + (size_t)r * DIN);
            float4 v0 = xp[0], v1 = xp[1], v2 = xp[2], v3 = xp[3], v4 = xp[4];
            float xv[20] = {v0.x, v0.y, v0.z, v0.w, v1.x, v1.y, v1.z, v1.w,
                            v2.x, v2.y, v2.z, v2.w, v3.x, v3.y, v3.z, v3.w,
                            v4.x, v4.y, v4.z, v4.w};
            float a0 = 0.f, a1 = 0.f, b0 = 0.f, b1 = 0.f;
            #pragma unroll
            for (int k = 0; k < DIN; k++) {
                float xvk = xv[k];
                a0 += xvk * fv[k * 4 + 0];
                a1 += xvk * fv[k * 4 + 1];
                b0 += xvk * fv[k * 4 + 2];
                b1 += xvk * fv[k * 4 + 3];
            }
            ((float2*)a_d)[r]  = make_float2(a0 + fv[80], a1 + fv[81]);
            ((float2*)advd)[r] = make_float2(b0 + fv[82], b1 + fv[83]);
        }
        return;
    }
    // ---- ingredient role ----
    float* u1s = (float*)sm;           // 256 floats
    float* Ts  = u1s + 256;            // 512 floats
    u1s[t] = stats[1200 + t];
    Ts[t] = stats[1712 + t];
    Ts[256 + t] = stats[1968 + t];
    __syncthreads();
    int r = t >> 3, cg = t & 7;
    int row = (bid - A2B - R0B) * 32 + r;
    float as0 = 0.f, as1 = 0.f, p00 = 0.f, p01 = 0.f, p10 = 0.f, p11 = 0.f;
    if (row < NI) {
        const float* xp = ing_table + (size_t)ing_ids[row] * C + cg * 16;
        #pragma unroll
        for (int q = 0; q < 4; q++) {
            float4 v = ((const float4*)xp)[q];
            float xvv[4] = {v.x, v.y, v.z, v.w};
            #pragma unroll
            for (int jj = 0; jj < 4; jj++) {
                int k = cg * 16 + q * 4 + jj;
                float xx = xvv[jj];
                as0 += xx * u1s[k * 2 + 0];
                as1 += xx * u1s[k * 2 + 1];
                p00 += xx * Ts[k * 4 + 0];
                p01 += xx * Ts[k * 4 + 1];
                p10 += xx * Ts[k * 4 + 2];
                p11 += xx * Ts[k * 4 + 3];
            }
        }
    }
    #pragma unroll
    for (int m = 1; m <= 4; m <<= 1) {
        as0 += __shfl_xor(as0, m); as1 += __shfl_xor(as1, m);
        p00 += __shfl_xor(p00, m); p01 += __shfl_xor(p01, m);
        p10 += __shfl_xor(p10, m); p11 += __shfl_xor(p11, m);
    }
    if (cg == 0 && row < NI) {
        ((float2*)a_si)[row] = make_float2(as0, as1);
        float4 pv; pv.x = p00; pv.y = p01; pv.z = p10; pv.w = p11;
        ((float4*)psi)[row] = pv;
    }
}

// ---------------- K_fin: kB fine sort ∥ user hs MFMA ------------------------------
// blocks [0,NB): kB; [NB,NB+HB): user-hs
__global__ __launch_bounds__(256) void k_fin(const u64* __restrict__ pairs,
    const u32* __restrict__ bucketBase, int n2, int NB,
    int* __restrict__ off, int* __restrict__ sorted,
    const float* __restrict__ user_table, const int* __restrict__ user_ids, int NU,
    const u16* __restrict__ wsp, const float* __restrict__ stats,
    u16* __restrict__ hs16, float* __restrict__ a_su)
{
    __shared__ __align__(16) char sm[30736];
    int t = threadIdx.x;
    int bid = blockIdx.x;
    if (bid < NB) {
        u32* cntA = (u32*)sm;          // 2048
        u32* cntB = cntA + 512;        // 2048
        u32* offL = cntB + 512;        // 2048
        u32* wsum4 = offL + 512;       // 16
        u32* ldsS = wsum4 + 4;         // 6144 * 4 = 24576
        int b = bid;
        u32 beg = bucketBase[b], end = bucketBase[b + 1];
        int dstBase = b << 9;
        for (int i = t; i < 512; i += 256) { cntA[i] = 0; cntB[i] = 0; }
        __syncthreads();
        for (u32 j = beg + t; j < end; j += 256) {
            u32 key = (u32)(pairs[j] >> 32);
            atomicAdd(&cntA[key - dstBase], 1u);
        }
        __syncthreads();
        scan512f(cntA, offL, wsum4);
        for (int d = t; d < 512; d += 256) {
            int gk = dstBase + d;
            if (gk < n2) off[gk] = (int)(beg + offL[d]);
        }
        u32 cnt = end - beg;
        bool fast = cnt <= 6144u;
        __syncthreads();
        for (u32 j = beg + t; j < end; j += 256) {
            u64 e = pairs[j];
            u32 d = (u32)(e >> 32) - dstBase;
            u32 r = atomicAdd(&cntB[d], 1u);
            u32 pos = offL[d] + r;
            if (fast) ldsS[pos] = (u32)e;
            else sorted[beg + pos] = (int)(u32)e;
        }
        __syncthreads();
        if (fast) {
            for (u32 j = t; j < cnt; j += 256) sorted[beg + j] = (int)ldsS[j];
        }
        return;
    }
    // ---- user hs MFMA role ----
    u16* A = (u16*)sm;                       // 32*136*2 = 8704 B
    float* u2s = (float*)(sm + 8704);        // 1024 B
    u2s[t] = stats[1456 + t];
    int rowBase = (bid - NB) * 32;
    int r = t >> 3, cg = t & 7;
    int row = rowBase + r;
    float xv[16];
    if (row < NU) {
        const float* xp = user_table + (size_t)user_ids[row] * C + cg * 16;
        #pragma unroll
        for (int q = 0; q < 4; q++) {
            float4 v = ((const float4*)xp)[q];
            xv[q * 4 + 0] = v.x; xv[q * 4 + 1] = v.y;
            xv[q * 4 + 2] = v.z; xv[q * 4 + 3] = v.w;
        }
    } else {
        #pragma unroll
        for (int q = 0; q < 16; q++) xv[q] = 0.f;
    }
    float ss = 0.f;
    #pragma unroll
    for (int q = 0; q < 16; q++) ss += xv[q] * xv[q];
    #pragma unroll
    for (int m = 1; m <= 4; m <<= 1) ss += __shfl_xor(ss, m);
    float nn = sqrtf(ss);
    float f = (nn > 1.f) ? 1.f / (nn + 1e-7f) : 1.f;
    float as0 = 0.f, as1 = 0.f;
    #pragma unroll
    for (int q = 0; q < 16; q++) {
        xv[q] *= f;
        int k = cg * 16 + q;
        as0 += xv[q] * u2s[k * 2 + 0];
        as1 += xv[q] * u2s[k * 2 + 1];
    }
    #pragma unroll
    for (int m = 1; m <= 4; m <<= 1) {
        as0 += __shfl_xor(as0, m); as1 += __shfl_xor(as1, m);
    }
    if (cg == 0 && row < NU) ((float2*)a_su)[row] = make_float2(as0, as1);
    {
        union { u16 h[16]; uint4 u4[2]; } pk;
        #pragma unroll
        for (int q = 0; q < 16; q++) pk.h[q] = f2bf_rne(xv[q]);
        uint4* dst = (uint4*)&A[r * 136 + cg * 16];
        dst[0] = pk.u4[0];
        dst[1] = pk.u4[1];
    }
    __syncthreads();
    int w = t >> 6, l = t & 63;
    int m15 = l & 15, q4 = l >> 4;
    bf16x8 afrag[2][4];
    #pragma unroll
    for (int mt = 0; mt < 2; mt++)
        #pragma unroll
        for (int kb = 0; kb < 4; kb++)
            afrag[mt][kb] = *(const bf16x8*)&A[(mt * 16 + m15) * 136 + kb * 32 + q4 * 8];
    f32x4 acc[2][4];
    #pragma unroll
    for (int mt = 0; mt < 2; mt++)
        #pragma unroll
        for (int i = 0; i < 4; i++) acc[mt][i] = (f32x4){0.f, 0.f, 0.f, 0.f};
    #pragma unroll
    for (int kb = 0; kb < 4; kb++) {
        #pragma unroll
        for (int i = 0; i < 4; i++) {
            int nt = w * 4 + i;
            bf16x8 bfrag = *(const bf16x8*)&wsp[((nt * 4 + kb) * 64 + l) * 8];
            acc[0][i] = __builtin_amdgcn_mfma_f32_16x16x32_bf16(afrag[0][kb], bfrag, acc[0][i], 0, 0, 0);
            acc[1][i] = __builtin_amdgcn_mfma_f32_16x16x32_bf16(afrag[1][kb], bfrag, acc[1][i], 0, 0, 0);
        }
    }
    #pragma unroll
    for (int mt = 0; mt < 2; mt++) {
        #pragma unroll
        for (int i = 0; i < 4; i++) {
            int col = (w * 4 + i) * 16 + m15;
            #pragma unroll
            for (int rr = 0; rr < 4; rr++) {
                int rw = rowBase + mt * 16 + q4 * 4 + rr;
                if (rw < NU) hs16[(size_t)rw * HC + col] = f2bf_rne(acc[mt][i][rr]);
            }
        }
    }
}

// ---------------- Fused aggregation: GAT1 (psi) then GAT2 (R4 uint2 gather) -------
__global__ __launch_bounds__(256) void k_agg(const int* __restrict__ off, const int* __restrict__ sorted,
    const float* __restrict__ a_si, const float* __restrict__ psi,
    const float* __restrict__ a_d1, const float* __restrict__ advd,
    const float* __restrict__ cb,
    const float* __restrict__ a_su, const u16* __restrict__ hs16,
    const float* __restrict__ bias, int NR, float* __restrict__ out)
{
    int wave = threadIdx.x >> 6, lane = threadIdx.x & 63;
    int d = blockIdx.x * 4 + wave;
    if (d >= NR) return;
    // ---------- phase 1: GAT1 psi aggregation ----------
    int beg = off[d], end = off[d + 1];
    float ad0 = a_d1[d * 2 + 0], ad1 = a_d1[d * 2 + 1];
    float w0s = 0.f, w1s = 0.f, a00 = 0.f, a01 = 0.f, a10 = 0.f, a11 = 0.f;
    for (int j = beg + lane; j < end; j += 64) {
        int s = sorted[j];
        float2 as = ((const float2*)a_si)[s];
        float e0 = as.x + ad0; e0 = (e0 >= 0.f) ? e0 : 0.2f * e0;
        float e1 = as.y + ad1; e1 = (e1 >= 0.f) ? e1 : 0.2f * e1;
        float x0 = __expf(e0), x1 = __expf(e1);
        float4 p = ((const float4*)psi)[s];
        w0s += x0; w1s += x1;
        a00 += x0 * p.x; a01 += x0 * p.y;
        a10 += x1 * p.z; a11 += x1 * p.w;
    }
    #pragma unroll
    for (int o = 1; o < 64; o <<= 1) {
        w0s += __shfl_xor(w0s, o); w1s += __shfl_xor(w1s, o);
        a00 += __shfl_xor(a00, o); a01 += __shfl_xor(a01, o);
        a10 += __shfl_xor(a10, o); a11 += __shfl_xor(a11, o);
    }
    float inv0g = 1.f / (w0s + 1e-16f), inv1g = 1.f / (w1s + 1e-16f);
    float r0 = advd[d * 2 + 0] + cb[0] + 0.5f * (a00 * inv0g + a10 * inv1g);
    float r1 = advd[d * 2 + 1] + cb[1] + 0.5f * (a01 * inv0g + a11 * inv1g);
    // ---------- phase 2: GAT2 hs16 row gather (R4 uint2 1-edge/step) ----------
    int beg2 = off[NR + d], end2 = off[NR + d + 1];
    int head = lane >> 5;
    int q = lane & 31;
    u32 laneoff = (u32)(head * 256 + q * 8);
    int hsel = lane & 32;
    float adh = head ? r1 : r0;
    float wsum = 0.f;
    float acc0 = 0.f, acc1 = 0.f, acc2 = 0.f, acc3 = 0.f;
    const char* hbase = (const char*)hs16;

    for (int base = beg2; base < end2; base += 32) {
        int rem = end2 - base; if (rem > 32) rem = 32;
        int j = q; if (j >= rem) j = rem - 1;
        int sp = sorted[base + j];
        u32 boff = ((u32)sp) << 9;
        float asv = a_su[sp * 2 + head];
        float ee = asv + adh; ee = (ee >= 0.f) ? ee : 0.2f * ee;
        float wcomb = __expf(ee);
        int e = 0;
        for (; e + 4 <= rem; e += 4) {
            u32 b0 = __shfl(boff, e + 0), b1 = __shfl(boff, e + 1);
            u32 b2 = __shfl(boff, e + 2), b3 = __shfl(boff, e + 3);
            uint2 g0 = *(const uint2*)(hbase + (b0 + laneoff));
            uint2 g1 = *(const uint2*)(hbase + (b1 + laneoff));
            uint2 g2 = *(const uint2*)(hbase + (b2 + laneoff));
            uint2 g3 = *(const uint2*)(hbase + (b3 + laneoff));
            float W0 = __shfl(wcomb, hsel + e + 0);
            float W1 = __shfl(wcomb, hsel + e + 1);
            float W2 = __shfl(wcomb, hsel + e + 2);
            float W3 = __shfl(wcomb, hsel + e + 3);
            wsum += (W0 + W1) + (W2 + W3);
            acc0 += W0 * bfbits2f(g0.x & 0xFFFFu);
            acc1 += W0 * __uint_as_float(g0.x & 0xFFFF0000u);
            acc2 += W0 * bfbits2f(g0.y & 0xFFFFu);
            acc3 += W0 * __uint_as_float(g0.y & 0xFFFF0000u);
            acc0 += W1 * bfbits2f(g1.x & 0xFFFFu);
            acc1 += W1 * __uint_as_float(g1.x & 0xFFFF0000u);
            acc2 += W1 * bfbits2f(g1.y & 0xFFFFu);
            acc3 += W1 * __uint_as_float(g1.y & 0xFFFF0000u);
            acc0 += W2 * bfbits2f(g2.x & 0xFFFFu);
            acc1 += W2 * __uint_as_float(g2.x & 0xFFFF0000u);
            acc2 += W2 * bfbits2f(g2.y & 0xFFFFu);
            acc3 += W2 * __uint_as_float(g2.y & 0xFFFF0000u);
            acc0 += W3 * bfbits2f(g3.x & 0xFFFFu);
            acc1 += W3 * __uint_as_float(g3.x & 0xFFFF0000u);
            acc2 += W3 * bfbits2f(g3.y & 0xFFFFu);
            acc3 += W3 * __uint_as_float(g3.y & 0xFFFF0000u);
        }
        for (; e < rem; e++) {
            u32 b0 = __shfl(boff, e);
            float W = __shfl(wcomb, hsel + e);
            uint2 g = *(const uint2*)(hbase + (b0 + laneoff));
            wsum += W;
            acc0 += W * bfbits2f(g.x & 0xFFFFu);
            acc1 += W * __uint_as_float(g.x & 0xFFFF0000u);
            acc2 += W * bfbits2f(g.y & 0xFFFFu);
            acc3 += W * __uint_as_float(g.y & 0xFFFF0000u);
        }
    }
    float inv = 1.f / (wsum + 1e-16f);
    float v0 = acc0 * inv, v1 = acc1 * inv, v2 = acc2 * inv, v3 = acc3 * inv;
    v0 = 0.5f * (v0 + __shfl_xor(v0, 32));
    v1 = 0.5f * (v1 + __shfl_xor(v1, 32));
    v2 = 0.5f * (v2 + __shfl_xor(v2, 32));
    v3 = 0.5f * (v3 + __shfl_xor(v3, 32));
    if (lane < 32) {
        float4 bb = ((const float4*)bias)[q];
        float4 o;
        o.x = v0 + bb.x; o.y = v1 + bb.y; o.z = v2 + bb.z; o.w = v3 + bb.w;
        ((float4*)(out + (size_t)d * C))[q] = o;
    }
}

extern "C" void kernel_launch(void* const* d_in, const int* in_sizes, int n_in,
                              void* d_out, int out_size, void* d_ws, size_t ws_size,
                              hipStream_t stream) {
    const int*   user_ids       = (const int*)d_in[0];
    const int*   ingredient_ids = (const int*)d_in[1];
    const float* recipe_x       = (const float*)d_in[2];
    const int*   ing_src        = (const int*)d_in[3];
    const int*   ing_dst        = (const int*)d_in[4];
    const int*   ub_src         = (const int*)d_in[5];
    const int*   ub_dst         = (const int*)d_in[6];
    const float* user_table     = (const float*)d_in[7];
    const float* ing_table      = (const float*)d_in[8];
    const float* W_rl           = (const float*)d_in[9];
    const float* bn_gamma       = (const float*)d_in[11];
    const float* bn_beta        = (const float*)d_in[12];
    const float* g1_ws          = (const float*)d_in[13];
    const float* g1_wd          = (const float*)d_in[14];
    const float* g1_as          = (const float*)d_in[15];
    const float* g1_ad          = (const float*)d_in[16];
    const float* g1_b           = (const float*)d_in[17];
    const float* g2_ws          = (const float*)d_in[18];
    const float* g2_wd          = (const float*)d_in[19];
    const float* g2_as          = (const float*)d_in[20];
    const float* g2_ad          = (const float*)d_in[21];
    const float* g2_b           = (const float*)d_in[22];

    int NU = in_sizes[0];
    int NI = in_sizes[1];
    int NR = in_sizes[2] / DIN;
    int E1 = in_sizes[3];
    int E2 = in_sizes[5];
    int Nmax = (NI > NU) ? NI : NU;
    int L1 = (NI < NR) ? NI : NR;
    int L2 = (NU < NR) ? NU : NR;
    int Etot = E1 + L1 + E2 + L2;
    int n2 = 2 * NR;
    int NB = (n2 + 511) >> 9;

    char* w = (char*)d_ws;
    u16*   hs16  = (u16*)w;    w += (size_t)Nmax * HC * 2;
    float* a_si  = (float*)w;  w += (size_t)NI * 2 * 4;
    float* a_su  = (float*)w;  w += (size_t)NU * 2 * 4;
    float* psi   = (float*)w;  w += (size_t)NI * 4 * 4;
    float* a_d   = (float*)w;  w += (size_t)NR * 2 * 4;
    float* advd  = (float*)w;  w += (size_t)NR * 2 * 4;
    float* stats = (float*)w;  w += 2432 * 4;
    u32*   bucketCnt  = (u32*)w; w += MAXNB * 4;     // adjacent to stats: one memset
    u16*   wsp   = (u16*)w;    w += 32768 * 2;
    u32*   bucketBase = (u32*)w; w += (MAXNB + 1) * 4;
    u32*   gcur  = (u32*)w;    w += MAXNB * 4;
    int*   off   = (int*)w;    w += (size_t)(n2 + 1) * 4;
    int*   sorted= (int*)w;    w += (size_t)Etot * 4;
    w = (char*)(((size_t)w + 15) & ~(size_t)15);
    u64*   pairs = (u64*)w;    w += (size_t)Etot * 8;

    hipMemsetAsync(stats, 0, (2432 + MAXNB) * 4, stream);

    int SB = (NR + 255) / 256;
    int AB = (Etot + EB1 - 1) / EB1;
    // L1: BN stats + dst histogram + B-pack
    k_init<<<SB + AB + 32, 256, 0, stream>>>(recipe_x, NR, stats, SB, AB,
                                             ing_dst, ub_dst, E1, L1, E2, L2, NB,
                                             bucketCnt, g2_ws, wsp);
    // L2: precomp + bucket scan (2 blocks)
    k_scanpre<<<2, 256, 0, stream>>>(stats, W_rl, bn_gamma, bn_beta,
                                     g1_wd, g1_ad, g2_wd, g2_ad,
                                     g1_ws, g1_as, g2_ws, g2_as, g1_b,
                                     1.0f / NR,
                                     bucketCnt, NB, n2, bucketBase, gcur, off);
    // L3: kA2 counting sort ∥ r0f GEMV ∥ ingredient psi
    int A2B = (Etot + EB2 - 1) / EB2;
    int R0B = (NR + 255) / 256;
    int IB  = (NI + 31) / 32;
    k_mid<<<A2B + R0B + IB, 256, 0, stream>>>(ing_src, ing_dst, ub_src, ub_dst,
                                              E1, L1, E2, L2, NR, NB, gcur, pairs,
                                              A2B, R0B, recipe_x, stats, a_d, advd,
                                              ing_table, ingredient_ids, NI, a_si, psi);
    // L4: kB fine sort ∥ user hs MFMA
    int HB = (NU + 31) / 32;
    k_fin<<<NB + HB, 256, 0, stream>>>(pairs, bucketBase, n2, NB, off, sorted,
                                       user_table, user_ids, NU, wsp, stats,
                                       hs16, a_su);
    // L5: fused GAT1 + GAT2 aggregation
    k_agg<<<(NR + 3) / 4, 256, 0, stream>>>(off, sorted, a_si, psi, a_d, advd,
                                            stats + 1188, a_su, hs16, g2_b, NR,
                                            (float*)d_out);
}

// Round 8
// 319.125 us; speedup vs baseline: 1.1253x; 1.1253x over previous
//
#include <hip/hip_runtime.h>
#include <hip/hip_bf16.h>
#include <math.h>

#define DIN 20
#define C 128
#define HC 256
#define EB2 1024
#define MAXNB 400
#define CAP 8192
#define CAPSH 13

typedef unsigned short u16;
typedef unsigned int u32;
typedef unsigned long long u64;
typedef __bf16 bf16x8 __attribute__((ext_vector_type(8)));
typedef float f32x4 __attribute__((ext_vector_type(4)));

__device__ __forceinline__ float bfbits2f(unsigned int lo16) {
    return __uint_as_float(lo16 << 16);
}
__device__ __forceinline__ u16 f2bf_rne(float f) {
    unsigned int b = __float_as_uint(f);
    return (u16)((b + 0x7FFFu + ((b >> 16) & 1u)) >> 16);
}

// exclusive scan of cnt[0..511] -> off[0..511]; wave-shuffle scan, 2 barriers
__device__ __forceinline__ void scan512f(u32* cnt, u32* off, u32* wsum4) {
    int t = threadIdx.x;
    int l = t & 63, w = t >> 6;
    u32 a = cnt[2 * t], b = cnt[2 * t + 1];
    u32 s = a + b;
    u32 isc = s;
    #pragma unroll
    for (int o = 1; o < 64; o <<= 1) {
        u32 n = __shfl_up(isc, o);
        if (l >= o) isc += n;
    }
    if (l == 63) wsum4[w] = isc;
    __syncthreads();
    u32 pre = 0;
    if (w > 0) pre += wsum4[0];
    if (w > 1) pre += wsum4[1];
    if (w > 2) pre += wsum4[2];
    u32 excl = pre + isc - s;
    off[2 * t] = excl;
    off[2 * t + 1] = excl + a;
    __syncthreads();
}

__device__ __forceinline__ void edge_at(int i, const int* s1, const int* d1,
    const int* s2, const int* d2, int E1, int T1, int E2, int NR,
    int& s, int& key)
{
    if (i < T1) {
        if (i < E1) { s = s1[i]; key = d1[i]; }
        else        { s = i - E1; key = i - E1; }
    } else {
        int k = i - T1;
        if (k < E2) { s = s2[k]; key = NR + d2[k]; }
        else        { s = k - E2; key = NR + (k - E2); }
    }
}

// ---------------- L1: BN stats ∥ kA2 bucket-sort (capacity-strided) ∥ B-pack ------
// blocks [0,SB): BN stats; [SB,SB+A2B): kA2; [SB+A2B,+32): pack
__global__ __launch_bounds__(256) void k_init(const float* __restrict__ x, int NR,
    float* __restrict__ stats, int SB, int A2B,
    const int* __restrict__ src1, const int* __restrict__ dst1,
    const int* __restrict__ src2, const int* __restrict__ dst2,
    int E1, int L1, int E2, int L2, int NB,
    u32* __restrict__ bucketFill, u64* __restrict__ pairs,
    const float* __restrict__ g2_ws, u16* __restrict__ wsp)
{
    __shared__ __align__(16) char sm[24144];
    int t = threadIdx.x;
    int bid = blockIdx.x;
    if (bid < SB) {
        // ---- BN stats role ----
        float (*L)[DIN] = (float(*)[DIN])sm;
        int r = bid * 256 + t;
        if (r < NR) {
            #pragma unroll
            for (int k = 0; k < DIN; k++) L[t][k] = x[r * DIN + k];
        } else {
            #pragma unroll
            for (int k = 0; k < DIN; k++) L[t][k] = 0.f;
        }
        __syncthreads();
        if (t < 210) {
            int p = 0, q = t;
            while (q >= DIN - p) { q -= (DIN - p); p++; }
            q += p;
            float acc = 0.f;
            for (int rr = 0; rr < 256; rr++) acc += L[rr][p] * L[rr][q];
            atomicAdd(&stats[p * DIN + q], acc);
            if (p != q) atomicAdd(&stats[q * DIN + p], acc);
        } else if (t < 230) {
            int k = t - 210;
            float acc = 0.f;
            for (int rr = 0; rr < 256; rr++) acc += L[rr][k];
            atomicAdd(&stats[400 + k], acc);
        }
        return;
    }
    if (bid < SB + A2B) {
        // ---- kA2 role: LDS counting sort by bucket, runs appended at
        //      b*CAP + atomicAdd(fill[b]) (contiguous-run global writes) ----
        u64* ldsE = (u64*)sm;                    // 1024*8 = 8192
        u64* ldsS = ldsE + EB2;                  // 8192
        u32* cntA = (u32*)(ldsS + EB2);          // 2048
        u32* cntB = cntA + 512;                  // 2048
        u32* offL = cntB + 512;                  // 2048
        u32* wsum4 = offL + 512;                 // 16
        u32* gbase = wsum4 + 4;                  // 1600
        for (int i = t; i < 512; i += 256) { cntA[i] = 0; cntB[i] = 0; }
        __syncthreads();
        int T1 = E1 + L1, T = T1 + E2 + L2;
        int base = (bid - SB) * EB2;
        int nE = T - base; if (nE > EB2) nE = EB2;
        for (int j = t; j < nE; j += 256) {
            int s, key;
            edge_at(base + j, src1, dst1, src2, dst2, E1, T1, E2, NR, s, key);
            ldsE[j] = ((u64)(u32)key << 32) | (u32)s;
            atomicAdd(&cntA[key >> 9], 1u);
        }
        __syncthreads();
        scan512f(cntA, offL, wsum4);
        for (int b = t; b < NB; b += 256) {
            u32 c = cntA[b];
            gbase[b] = c ? (((u32)b << CAPSH) + atomicAdd(&bucketFill[b], c)) : 0u;
        }
        __syncthreads();
        for (int j = t; j < nE; j += 256) {
            u64 e = ldsE[j];
            u32 b = ((u32)(e >> 32)) >> 9;
            u32 r = atomicAdd(&cntB[b], 1u);
            ldsS[offL[b] + r] = e;
        }
        __syncthreads();
        for (int j = t; j < nE; j += 256) {
            u64 e = ldsS[j];
            u32 b = ((u32)(e >> 32)) >> 9;
            pairs[gbase[b] + ((u32)j - offL[b])] = e;
        }
        return;
    }
    // ---- B-pack role (32 blocks) ----
    int idx0 = ((bid - SB - A2B) * 256 + t) * 4;
    #pragma unroll
    for (int i = 0; i < 4; i++) {
        int flat = idx0 + i;           // [nt(16)][kb(4)][lane(64)][j(8)]
        int j = flat & 7;
        int lane = (flat >> 3) & 63;
        int kb = (flat >> 9) & 3;
        int nt = flat >> 11;
        int k = kb * 32 + (lane >> 4) * 8 + j;
        int n = nt * 16 + (lane & 15);
        wsp[flat] = f2bf_rne(g2_ws[k * HC + n]);
    }
}

// ---------------- L2: precomp (single block) --------------------------------------
__global__ __launch_bounds__(256) void k_pre(float* __restrict__ stats,
    const float* __restrict__ W,
    const float* __restrict__ gamma, const float* __restrict__ beta,
    const float* __restrict__ g1_wd, const float* __restrict__ g1_ad,
    const float* __restrict__ g2_wd, const float* __restrict__ g2_ad,
    const float* __restrict__ g1_ws, const float* __restrict__ g1_as,
    const float* __restrict__ g2_ws, const float* __restrict__ g2_as,
    const float* __restrict__ g1b, float invN)
{
    int t = threadIdx.x;
    __shared__ float Sm[420];
    __shared__ float Wm[DIN * C];
    __shared__ float vd1s[256];
    __shared__ float vd2s[256];
    __shared__ float sS[128];
    __shared__ float sSh[128];
    for (int i = t; i < 420; i += 256) Sm[i] = stats[i];
    for (int i = t; i < DIN * C; i += 256) Wm[i] = W[i];
    __syncthreads();
    if (t < C) {
        float w[DIN];
        #pragma unroll
        for (int k = 0; k < DIN; k++) w[k] = Wm[k * C + t];
        float mb = 0.f;
        #pragma unroll
        for (int k = 0; k < DIN; k++) mb += Sm[400 + k] * invN * w[k];
        float e2 = 0.f;
        for (int p = 0; p < DIN; p++) {
            float acc2 = 0.f;
            #pragma unroll
            for (int q = 0; q < DIN; q++) acc2 += Sm[p * DIN + q] * w[q];
            e2 += w[p] * acc2;
        }
        e2 *= invN;
        float var = e2 - mb * mb;
        float s = gamma[t] * rsqrtf(var + 1e-5f);
        float sh = beta[t] - s * mb;   // b_rl cancels inside BN
        stats[420 + t] = s;
        stats[548 + t] = sh;
        sS[t] = s;
        sSh[t] = sh;
    }
    {
        int k = t >> 1, h = t & 1;
        const float4* wd1 = (const float4*)(g1_wd + k * HC + h * C);
        const float4* wd2 = (const float4*)(g2_wd + k * HC + h * C);
        const float4* ws1 = (const float4*)(g1_ws + k * HC + h * C);
        const float4* ws2 = (const float4*)(g2_ws + k * HC + h * C);
        const float4* ad1 = (const float4*)(g1_ad + h * C);
        const float4* ad2 = (const float4*)(g2_ad + h * C);
        const float4* as1 = (const float4*)(g1_as + h * C);
        const float4* as2 = (const float4*)(g2_as + h * C);
        float a1 = 0.f, a2 = 0.f, s1 = 0.f, s2 = 0.f;
        #pragma unroll 4
        for (int q = 0; q < 32; q++) {
            float4 x, y;
            x = wd1[q]; y = ad1[q];
            a1 += x.x * y.x + x.y * y.y + x.z * y.z + x.w * y.w;
            x = wd2[q]; y = ad2[q];
            a2 += x.x * y.x + x.y * y.y + x.z * y.z + x.w * y.w;
            x = ws1[q]; y = as1[q];
            s1 += x.x * y.x + x.y * y.y + x.z * y.z + x.w * y.w;
            x = ws2[q]; y = as2[q];
            s2 += x.x * y.x + x.y * y.y + x.z * y.z + x.w * y.w;
        }
        stats[676 + t] = a1;
        stats[932 + t] = a2;
        stats[1200 + t] = s1;
        stats[1456 + t] = s2;
        vd1s[t] = a1;
        vd2s[t] = a2;
    }
    __syncthreads();
    {
        int k = t >> 1, h = t & 1;
        const float4* ws1p = (const float4*)(g1_ws + k * HC + h * C);
        float t0 = 0.f, t1 = 0.f;
        #pragma unroll 4
        for (int q = 0; q < 32; q++) {
            float4 wv = ws1p[q];
            int c = q * 4;
            t0 += wv.x * vd2s[(c + 0) * 2 + 0] + wv.y * vd2s[(c + 1) * 2 + 0]
                + wv.z * vd2s[(c + 2) * 2 + 0] + wv.w * vd2s[(c + 3) * 2 + 0];
            t1 += wv.x * vd2s[(c + 0) * 2 + 1] + wv.y * vd2s[(c + 1) * 2 + 1]
                + wv.z * vd2s[(c + 2) * 2 + 1] + wv.w * vd2s[(c + 3) * 2 + 1];
        }
        stats[1712 + t * 2 + 0] = t0;
        stats[1712 + t * 2 + 1] = t1;
    }
    if (t < 2) {
        float cb = 0.f;
        for (int k = 0; k < C; k++) cb += g1b[k] * vd2s[k * 2 + t];
        stats[1188 + t] = cb;
    }
    if (t < 80) {
        int k = t >> 2, h4 = t & 3, h = h4 & 1;
        const float* vs = (h4 < 2) ? vd1s : vd2s;
        float acc = 0.f;
        for (int c = 0; c < C; c++) acc += sS[c] * Wm[k * C + c] * vs[c * 2 + h];
        stats[2240 + t] = acc;
    } else if (t < 84) {
        int h4 = t - 80, h = h4 & 1;
        const float* vs = (h4 < 2) ? vd1s : vd2s;
        float acc = 0.f;
        for (int c = 0; c < C; c++) acc += sSh[c] * vs[c * 2 + h];
        stats[2320 + h4] = acc;
    }
}

// ---------------- L3: kB fine sort ∥ r0f GEMV ∥ ing psi ∥ user hs MFMA ------------
// blocks [0,NB): kB -> off2/sorted; [NB,+R0B): r0f; [+IB): ing; [+HB): hs
__global__ __launch_bounds__(256) void k_fin(const u64* __restrict__ pairs,
    const u32* __restrict__ bucketFill, int n2, int NB, int R0B, int IB,
    int* __restrict__ off2, int* __restrict__ sorted,
    const float* __restrict__ x, int NR, const float* __restrict__ stats,
    float* __restrict__ a_d, float* __restrict__ advd,
    const float* __restrict__ ing_table, const int* __restrict__ ing_ids, int NI,
    float* __restrict__ a_si, float* __restrict__ psi,
    const float* __restrict__ user_table, const int* __restrict__ user_ids, int NU,
    const u16* __restrict__ wsp, u16* __restrict__ hs16, float* __restrict__ a_su)
{
    __shared__ __align__(16) char sm[30736];
    int t = threadIdx.x;
    int bid = blockIdx.x;
    if (bid < NB) {
        u32* cntA = (u32*)sm;          // 2048
        u32* cntB = cntA + 512;        // 2048
        u32* offL = cntB + 512;        // 2048
        u32* wsum4 = offL + 512;       // 16
        u32* ldsS = wsum4 + 4;         // 6144*4 = 24576
        int b = bid;
        u32 beg = (u32)b << CAPSH;
        u32 fill = bucketFill[b];
        u32 end = beg + fill;
        int dstBase = b << 9;
        for (int i = t; i < 512; i += 256) { cntA[i] = 0; cntB[i] = 0; }
        __syncthreads();
        for (u32 j = beg + t; j < end; j += 256) {
            u32 key = (u32)(pairs[j] >> 32);
            atomicAdd(&cntA[key - dstBase], 1u);
        }
        __syncthreads();
        scan512f(cntA, offL, wsum4);
        for (int d = t; d < 512; d += 256) {
            int gk = dstBase + d;
            if (gk < n2) {
                int s0 = (int)(beg + offL[d]);
                off2[2 * gk] = s0;
                off2[2 * gk + 1] = s0 + (int)cntA[d];
            }
        }
        bool fast = fill <= 6144u;
        __syncthreads();
        for (u32 j = beg + t; j < end; j += 256) {
            u64 e = pairs[j];
            u32 d = (u32)(e >> 32) - dstBase;
            u32 r = atomicAdd(&cntB[d], 1u);
            u32 pos = offL[d] + r;
            if (fast) ldsS[pos] = (u32)e;
            else sorted[beg + pos] = (int)(u32)e;
        }
        __syncthreads();
        if (fast) {
            for (u32 j = t; j < fill; j += 256) sorted[beg + j] = (int)ldsS[j];
        }
        return;
    }
    if (bid < NB + R0B) {
        // ---- r0f GEMV role ----
        float* fv = (float*)sm;
        if (t < 84) fv[t] = stats[2240 + t];
        __syncthreads();
        int r = (bid - NB) * 256 + t;
        if (r < NR) {
            const float4* xp = (const float4*)(x + (size_t)r * DIN);
            float4 v0 = xp[0], v1 = xp[1], v2 = xp[2], v3 = xp[3], v4 = xp[4];
            float xv[20] = {v0.x, v0.y, v0.z, v0.w, v1.x, v1.y, v1.z, v1.w,
                            v2.x, v2.y, v2.z, v2.w, v3.x, v3.y, v3.z, v3.w,
                            v4.x, v4.y, v4.z, v4.w};
            float a0 = 0.f, a1 = 0.f, b0 = 0.f, b1 = 0.f;
            #pragma unroll
            for (int k = 0; k < DIN; k++) {
                float xvk = xv[k];
                a0 += xvk * fv[k * 4 + 0];
                a1 += xvk * fv[k * 4 + 1];
                b0 += xvk * fv[k * 4 + 2];
                b1 += xvk * fv[k * 4 + 3];
            }
            ((float2*)a_d)[r]  = make_float2(a0 + fv[80], a1 + fv[81]);
            ((float2*)advd)[r] = make_float2(b0 + fv[82], b1 + fv[83]);
        }
        return;
    }
    if (bid < NB + R0B + IB) {
        // ---- ingredient role ----
        float* u1s = (float*)sm;
        float* Ts  = u1s + 256;
        u1s[t] = stats[1200 + t];
        Ts[t] = stats[1712 + t];
        Ts[256 + t] = stats[1968 + t];
        __syncthreads();
        int r = t >> 3, cg = t & 7;
        int row = (bid - NB - R0B) * 32 + r;
        float as0 = 0.f, as1 = 0.f, p00 = 0.f, p01 = 0.f, p10 = 0.f, p11 = 0.f;
        if (row < NI) {
            const float* xp = ing_table + (size_t)ing_ids[row] * C + cg * 16;
            #pragma unroll
            for (int q = 0; q < 4; q++) {
                float4 v = ((const float4*)xp)[q];
                float xvv[4] = {v.x, v.y, v.z, v.w};
                #pragma unroll
                for (int jj = 0; jj < 4; jj++) {
                    int k = cg * 16 + q * 4 + jj;
                    float xx = xvv[jj];
                    as0 += xx * u1s[k * 2 + 0];
                    as1 += xx * u1s[k * 2 + 1];
                    p00 += xx * Ts[k * 4 + 0];
                    p01 += xx * Ts[k * 4 + 1];
                    p10 += xx * Ts[k * 4 + 2];
                    p11 += xx * Ts[k * 4 + 3];
                }
            }
        }
        #pragma unroll
        for (int m = 1; m <= 4; m <<= 1) {
            as0 += __shfl_xor(as0, m); as1 += __shfl_xor(as1, m);
            p00 += __shfl_xor(p00, m); p01 += __shfl_xor(p01, m);
            p10 += __shfl_xor(p10, m); p11 += __shfl_xor(p11, m);
        }
        if (cg == 0 && row < NI) {
            ((float2*)a_si)[row] = make_float2(as0, as1);
            float4 pv; pv.x = p00; pv.y = p01; pv.z = p10; pv.w = p11;
            ((float4*)psi)[row] = pv;
        }
        return;
    }
    // ---- user hs MFMA role ----
    u16* A = (u16*)sm;                       // 32*136*2 = 8704 B
    float* u2s = (float*)(sm + 8704);        // 1024 B
    u2s[t] = stats[1456 + t];
    int rowBase = (bid - NB - R0B - IB) * 32;
    int r = t >> 3, cg = t & 7;
    int row = rowBase + r;
    float xv[16];
    if (row < NU) {
        const float* xp = user_table + (size_t)user_ids[row] * C + cg * 16;
        #pragma unroll
        for (int q = 0; q < 4; q++) {
            float4 v = ((const float4*)xp)[q];
            xv[q * 4 + 0] = v.x; xv[q * 4 + 1] = v.y;
            xv[q * 4 + 2] = v.z; xv[q * 4 + 3] = v.w;
        }
    } else {
        #pragma unroll
        for (int q = 0; q < 16; q++) xv[q] = 0.f;
    }
    float ss = 0.f;
    #pragma unroll
    for (int q = 0; q < 16; q++) ss += xv[q] * xv[q];
    #pragma unroll
    for (int m = 1; m <= 4; m <<= 1) ss += __shfl_xor(ss, m);
    float nn = sqrtf(ss);
    float f = (nn > 1.f) ? 1.f / (nn + 1e-7f) : 1.f;
    float as0 = 0.f, as1 = 0.f;
    #pragma unroll
    for (int q = 0; q < 16; q++) {
        xv[q] *= f;
        int k = cg * 16 + q;
        as0 += xv[q] * u2s[k * 2 + 0];
        as1 += xv[q] * u2s[k * 2 + 1];
    }
    #pragma unroll
    for (int m = 1; m <= 4; m <<= 1) {
        as0 += __shfl_xor(as0, m); as1 += __shfl_xor(as1, m);
    }
    if (cg == 0 && row < NU) ((float2*)a_su)[row] = make_float2(as0, as1);
    {
        union { u16 h[16]; uint4 u4[2]; } pk;
        #pragma unroll
        for (int q = 0; q < 16; q++) pk.h[q] = f2bf_rne(xv[q]);
        uint4* dst = (uint4*)&A[r * 136 + cg * 16];
        dst[0] = pk.u4[0];
        dst[1] = pk.u4[1];
    }
    __syncthreads();
    int w = t >> 6, l = t & 63;
    int m15 = l & 15, q4 = l >> 4;
    bf16x8 afrag[2][4];
    #pragma unroll
    for (int mt = 0; mt < 2; mt++)
        #pragma unroll
        for (int kb = 0; kb < 4; kb++)
            afrag[mt][kb] = *(const bf16x8*)&A[(mt * 16 + m15) * 136 + kb * 32 + q4 * 8];
    f32x4 acc[2][4];
    #pragma unroll
    for (int mt = 0; mt < 2; mt++)
        #pragma unroll
        for (int i = 0; i < 4; i++) acc[mt][i] = (f32x4){0.f, 0.f, 0.f, 0.f};
    #pragma unroll
    for (int kb = 0; kb < 4; kb++) {
        #pragma unroll
        for (int i = 0; i < 4; i++) {
            int nt = w * 4 + i;
            bf16x8 bfrag = *(const bf16x8*)&wsp[((nt * 4 + kb) * 64 + l) * 8];
            acc[0][i] = __builtin_amdgcn_mfma_f32_16x16x32_bf16(afrag[0][kb], bfrag, acc[0][i], 0, 0, 0);
            acc[1][i] = __builtin_amdgcn_mfma_f32_16x16x32_bf16(afrag[1][kb], bfrag, acc[1][i], 0, 0, 0);
        }
    }
    #pragma unroll
    for (int mt = 0; mt < 2; mt++) {
        #pragma unroll
        for (int i = 0; i < 4; i++) {
            int col = (w * 4 + i) * 16 + m15;
            #pragma unroll
            for (int rr = 0; rr < 4; rr++) {
                int rw = rowBase + mt * 16 + q4 * 4 + rr;
                if (rw < NU) hs16[(size_t)rw * HC + col] = f2bf_rne(acc[mt][i][rr]);
            }
        }
    }
}

// ---------------- L4: fused GAT1 (psi) then GAT2 (R4 uint2 gather) ----------------
__global__ __launch_bounds__(256) void k_agg(const int* __restrict__ off2, const int* __restrict__ sorted,
    const float* __restrict__ a_si, const float* __restrict__ psi,
    const float* __restrict__ a_d1, const float* __restrict__ advd,
    const float* __restrict__ cb,
    const float* __restrict__ a_su, const u16* __restrict__ hs16,
    const float* __restrict__ bias, int NR, float* __restrict__ out)
{
    int wave = threadIdx.x >> 6, lane = threadIdx.x & 63;
    int d = blockIdx.x * 4 + wave;
    if (d >= NR) return;
    // ---------- phase 1: GAT1 psi aggregation ----------
    int beg = off2[2 * d], end = off2[2 * d + 1];
    float ad0 = a_d1[d * 2 + 0], ad1 = a_d1[d * 2 + 1];
    float w0s = 0.f, w1s = 0.f, a00 = 0.f, a01 = 0.f, a10 = 0.f, a11 = 0.f;
    for (int j = beg + lane; j < end; j += 64) {
        int s = sorted[j];
        float2 as = ((const float2*)a_si)[s];
        float e0 = as.x + ad0; e0 = (e0 >= 0.f) ? e0 : 0.2f * e0;
        float e1 = as.y + ad1; e1 = (e1 >= 0.f) ? e1 : 0.2f * e1;
        float x0 = __expf(e0), x1 = __expf(e1);
        float4 p = ((const float4*)psi)[s];
        w0s += x0; w1s += x1;
        a00 += x0 * p.x; a01 += x0 * p.y;
        a10 += x1 * p.z; a11 += x1 * p.w;
    }
    #pragma unroll
    for (int o = 1; o < 64; o <<= 1) {
        w0s += __shfl_xor(w0s, o); w1s += __shfl_xor(w1s, o);
        a00 += __shfl_xor(a00, o); a01 += __shfl_xor(a01, o);
        a10 += __shfl_xor(a10, o); a11 += __shfl_xor(a11, o);
    }
    float inv0g = 1.f / (w0s + 1e-16f), inv1g = 1.f / (w1s + 1e-16f);
    float r0 = advd[d * 2 + 0] + cb[0] + 0.5f * (a00 * inv0g + a10 * inv1g);
    float r1 = advd[d * 2 + 1] + cb[1] + 0.5f * (a01 * inv0g + a11 * inv1g);
    // ---------- phase 2: GAT2 hs16 row gather (R4 uint2 1-edge/step) ----------
    int i2 = NR + d;
    int beg2 = off2[2 * i2], end2 = off2[2 * i2 + 1];
    int head = lane >> 5;
    int q = lane & 31;
    u32 laneoff = (u32)(head * 256 + q * 8);
    int hsel = lane & 32;
    float adh = head ? r1 : r0;
    float wsum = 0.f;
    float acc0 = 0.f, acc1 = 0.f, acc2 = 0.f, acc3 = 0.f;
    const char* hbase = (const char*)hs16;

    for (int base = beg2; base < end2; base += 32) {
        int rem = end2 - base; if (rem > 32) rem = 32;
        int j = q; if (j >= rem) j = rem - 1;
        int sp = sorted[base + j];
        u32 boff = ((u32)sp) << 9;
        float asv = a_su[sp * 2 + head];
        float ee = asv + adh; ee = (ee >= 0.f) ? ee : 0.2f * ee;
        float wcomb = __expf(ee);
        int e = 0;
        for (; e + 4 <= rem; e += 4) {
            u32 b0 = __shfl(boff, e + 0), b1 = __shfl(boff, e + 1);
            u32 b2 = __shfl(boff, e + 2), b3 = __shfl(boff, e + 3);
            uint2 g0 = *(const uint2*)(hbase + (b0 + laneoff));
            uint2 g1 = *(const uint2*)(hbase + (b1 + laneoff));
            uint2 g2 = *(const uint2*)(hbase + (b2 + laneoff));
            uint2 g3 = *(const uint2*)(hbase + (b3 + laneoff));
            float W0 = __shfl(wcomb, hsel + e + 0);
            float W1 = __shfl(wcomb, hsel + e + 1);
            float W2 = __shfl(wcomb, hsel + e + 2);
            float W3 = __shfl(wcomb, hsel + e + 3);
            wsum += (W0 + W1) + (W2 + W3);
            acc0 += W0 * bfbits2f(g0.x & 0xFFFFu);
            acc1 += W0 * __uint_as_float(g0.x & 0xFFFF0000u);
            acc2 += W0 * bfbits2f(g0.y & 0xFFFFu);
            acc3 += W0 * __uint_as_float(g0.y & 0xFFFF0000u);
            acc0 += W1 * bfbits2f(g1.x & 0xFFFFu);
            acc1 += W1 * __uint_as_float(g1.x & 0xFFFF0000u);
            acc2 += W1 * bfbits2f(g1.y & 0xFFFFu);
            acc3 += W1 * __uint_as_float(g1.y & 0xFFFF0000u);
            acc0 += W2 * bfbits2f(g2.x & 0xFFFFu);
            acc1 += W2 * __uint_as_float(g2.x & 0xFFFF0000u);
            acc2 += W2 * bfbits2f(g2.y & 0xFFFFu);
            acc3 += W2 * __uint_as_float(g2.y & 0xFFFF0000u);
            acc0 += W3 * bfbits2f(g3.x & 0xFFFFu);
            acc1 += W3 * __uint_as_float(g3.x & 0xFFFF0000u);
            acc2 += W3 * bfbits2f(g3.y & 0xFFFFu);
            acc3 += W3 * __uint_as_float(g3.y & 0xFFFF0000u);
        }
        for (; e < rem; e++) {
            u32 b0 = __shfl(boff, e);
            float W = __shfl(wcomb, hsel + e);
            uint2 g = *(const uint2*)(hbase + (b0 + laneoff));
            wsum += W;
            acc0 += W * bfbits2f(g.x & 0xFFFFu);
            acc1 += W * __uint_as_float(g.x & 0xFFFF0000u);
            acc2 += W * bfbits2f(g.y & 0xFFFFu);
            acc3 += W * __uint_as_float(g.y & 0xFFFF0000u);
        }
    }
    float inv = 1.f / (wsum + 1e-16f);
    float v0 = acc0 * inv, v1 = acc1 * inv, v2 = acc2 * inv, v3 = acc3 * inv;
    v0 = 0.5f * (v0 + __shfl_xor(v0, 32));
    v1 = 0.5f * (v1 + __shfl_xor(v1, 32));
    v2 = 0.5f * (v2 + __shfl_xor(v2, 32));
    v3 = 0.5f * (v3 + __shfl_xor(v3, 32));
    if (lane < 32) {
        float4 bb = ((const float4*)bias)[q];
        float4 o;
        o.x = v0 + bb.x; o.y = v1 + bb.y; o.z = v2 + bb.z; o.w = v3 + bb.w;
        ((float4*)(out + (size_t)d * C))[q] = o;
    }
}

extern "C" void kernel_launch(void* const* d_in, const int* in_sizes, int n_in,
                              void* d_out, int out_size, void* d_ws, size_t ws_size,
                              hipStream_t stream) {
    const int*   user_ids       = (const int*)d_in[0];
    const int*   ingredient_ids = (const int*)d_in[1];
    const float* recipe_x       = (const float*)d_in[2];
    const int*   ing_src        = (const int*)d_in[3];
    const int*   ing_dst        = (const int*)d_in[4];
    const int*   ub_src         = (const int*)d_in[5];
    const int*   ub_dst         = (const int*)d_in[6];
    const float* user_table     = (const float*)d_in[7];
    const float* ing_table      = (const float*)d_in[8];
    const float* W_rl           = (const float*)d_in[9];
    const float* bn_gamma       = (const float*)d_in[11];
    const float* bn_beta        = (const float*)d_in[12];
    const float* g1_ws          = (const float*)d_in[13];
    const float* g1_wd          = (const float*)d_in[14];
    const float* g1_as          = (const float*)d_in[15];
    const float* g1_ad          = (const float*)d_in[16];
    const float* g1_b           = (const float*)d_in[17];
    const float* g2_ws          = (const float*)d_in[18];
    const float* g2_wd          = (const float*)d_in[19];
    const float* g2_as          = (const float*)d_in[20];
    const float* g2_ad          = (const float*)d_in[21];
    const float* g2_b           = (const float*)d_in[22];

    int NU = in_sizes[0];
    int NI = in_sizes[1];
    int NR = in_sizes[2] / DIN;
    int E1 = in_sizes[3];
    int E2 = in_sizes[5];
    int Nmax = (NI > NU) ? NI : NU;
    int L1 = (NI < NR) ? NI : NR;
    int L2 = (NU < NR) ? NU : NR;
    int Etot = E1 + L1 + E2 + L2;
    int n2 = 2 * NR;
    int NB = (n2 + 511) >> 9;

    char* w = (char*)d_ws;
    u16*   hs16  = (u16*)w;    w += (size_t)Nmax * HC * 2;
    float* a_si  = (float*)w;  w += (size_t)NI * 2 * 4;
    float* a_su  = (float*)w;  w += (size_t)NU * 2 * 4;
    float* psi   = (float*)w;  w += (size_t)NI * 4 * 4;
    float* a_d   = (float*)w;  w += (size_t)NR * 2 * 4;
    float* advd  = (float*)w;  w += (size_t)NR * 2 * 4;
    float* stats = (float*)w;  w += 2432 * 4;
    u32*   bucketFill = (u32*)w; w += MAXNB * 4;     // adjacent to stats: one memset
    u16*   wsp   = (u16*)w;    w += 32768 * 2;
    int*   off2  = (int*)w;    w += (size_t)(2 * n2) * 4;
    int*   sorted= (int*)w;    w += (size_t)NB * CAP * 4;
    w = (char*)(((size_t)w + 15) & ~(size_t)15);
    u64*   pairs = (u64*)w;    w += (size_t)NB * CAP * 8;

    hipMemsetAsync(stats, 0, (2432 + MAXNB) * 4, stream);

    int SB  = (NR + 255) / 256;
    int A2B = (Etot + EB2 - 1) / EB2;
    // L1: BN stats ∥ kA2 capacity-strided bucket sort ∥ B-pack
    k_init<<<SB + A2B + 32, 256, 0, stream>>>(recipe_x, NR, stats, SB, A2B,
                                              ing_src, ing_dst, ub_src, ub_dst,
                                              E1, L1, E2, L2, NB,
                                              bucketFill, pairs, g2_ws, wsp);
    // L2: precomp (1 block)
    k_pre<<<1, 256, 0, stream>>>(stats, W_rl, bn_gamma, bn_beta,
                                 g1_wd, g1_ad, g2_wd, g2_ad,
                                 g1_ws, g1_as, g2_ws, g2_as, g1_b, 1.0f / NR);
    // L3: kB fine sort ∥ r0f GEMV ∥ ingredient psi ∥ user hs MFMA
    int R0B = (NR + 255) / 256;
    int IB  = (NI + 31) / 32;
    int HB  = (NU + 31) / 32;
    k_fin<<<NB + R0B + IB + HB, 256, 0, stream>>>(pairs, bucketFill, n2, NB, R0B, IB,
                                                  off2, sorted,
                                                  recipe_x, NR, stats, a_d, advd,
                                                  ing_table, ingredient_ids, NI, a_si, psi,
                                                  user_table, user_ids, NU,
                                                  wsp, hs16, a_su);
    // L4: fused GAT1 + GAT2 aggregation
    k_agg<<<(NR + 3) / 4, 256, 0, stream>>>(off2, sorted, a_si, psi, a_d, advd,
                                            stats + 1188, a_su, hs16, g2_b, NR,
                                            (float*)d_out);
}

// Round 9
// 300.729 us; speedup vs baseline: 1.1942x; 1.0612x over previous
//
#include <hip/hip_runtime.h>
#include <hip/hip_bf16.h>
#include <math.h>

#define DIN 20
#define C 128
#define HC 256
#define EB2 2048
#define MAXNB 400
#define CAP 8192
#define CAPSH 13

typedef unsigned short u16;
typedef unsigned int u32;
typedef unsigned long long u64;
typedef __bf16 bf16x8 __attribute__((ext_vector_type(8)));
typedef float f32x4 __attribute__((ext_vector_type(4)));

__device__ __forceinline__ float bfbits2f(unsigned int lo16) {
    return __uint_as_float(lo16 << 16);
}
__device__ __forceinline__ u16 f2bf_rne(float f) {
    unsigned int b = __float_as_uint(f);
    return (u16)((b + 0x7FFFu + ((b >> 16) & 1u)) >> 16);
}

// exclusive scan of cnt[0..511] -> off[0..511]; wave-shuffle scan, 2 barriers
__device__ __forceinline__ void scan512f(u32* cnt, u32* off, u32* wsum4) {
    int t = threadIdx.x;
    int l = t & 63, w = t >> 6;
    u32 a = cnt[2 * t], b = cnt[2 * t + 1];
    u32 s = a + b;
    u32 isc = s;
    #pragma unroll
    for (int o = 1; o < 64; o <<= 1) {
        u32 n = __shfl_up(isc, o);
        if (l >= o) isc += n;
    }
    if (l == 63) wsum4[w] = isc;
    __syncthreads();
    u32 pre = 0;
    if (w > 0) pre += wsum4[0];
    if (w > 1) pre += wsum4[1];
    if (w > 2) pre += wsum4[2];
    u32 excl = pre + isc - s;
    off[2 * t] = excl;
    off[2 * t + 1] = excl + a;
    __syncthreads();
}

__device__ __forceinline__ void edge_at(int i, const int* s1, const int* d1,
    const int* s2, const int* d2, int E1, int T1, int E2, int NR,
    int& s, int& key)
{
    if (i < T1) {
        if (i < E1) { s = s1[i]; key = d1[i]; }
        else        { s = i - E1; key = i - E1; }
    } else {
        int k = i - T1;
        if (k < E2) { s = s2[k]; key = NR + d2[k]; }
        else        { s = k - E2; key = NR + (k - E2); }
    }
}

// ---- L1: BN stats ∥ kA2 bucket-sort (EB2=2048, capacity-strided) ∥ B-pack ∥ dots -
// blocks [0,SB): BN; [SB,+A2B): kA2; [+32): pack; [+4): attention dot-products
__global__ __launch_bounds__(256) void k_init(const float* __restrict__ x, int NR,
    float* __restrict__ stats, int SB, int A2B,
    const int* __restrict__ src1, const int* __restrict__ dst1,
    const int* __restrict__ src2, const int* __restrict__ dst2,
    int E1, int L1, int E2, int L2, int NB,
    u32* __restrict__ bucketFill, u64* __restrict__ pairs,
    const float* __restrict__ g2_ws, u16* __restrict__ wsp,
    const float* __restrict__ g1_wd, const float* __restrict__ g1_ad,
    const float* __restrict__ g2_wd, const float* __restrict__ g2_ad,
    const float* __restrict__ g1_ws, const float* __restrict__ g1_as,
    const float* __restrict__ g2_as)
{
    __shared__ __align__(16) char sm[40528];
    int t = threadIdx.x;
    int bid = blockIdx.x;
    if (bid < SB) {
        // ---- BN stats role (vectorized row load) ----
        float (*L)[DIN] = (float(*)[DIN])sm;
        int r = bid * 256 + t;
        if (r < NR) {
            const float4* xp = (const float4*)(x + (size_t)r * DIN);
            float4 v0 = xp[0], v1 = xp[1], v2 = xp[2], v3 = xp[3], v4 = xp[4];
            L[t][0] = v0.x; L[t][1] = v0.y; L[t][2] = v0.z; L[t][3] = v0.w;
            L[t][4] = v1.x; L[t][5] = v1.y; L[t][6] = v1.z; L[t][7] = v1.w;
            L[t][8] = v2.x; L[t][9] = v2.y; L[t][10] = v2.z; L[t][11] = v2.w;
            L[t][12] = v3.x; L[t][13] = v3.y; L[t][14] = v3.z; L[t][15] = v3.w;
            L[t][16] = v4.x; L[t][17] = v4.y; L[t][18] = v4.z; L[t][19] = v4.w;
        } else {
            #pragma unroll
            for (int k = 0; k < DIN; k++) L[t][k] = 0.f;
        }
        __syncthreads();
        if (t < 210) {
            int p = 0, q = t;
            while (q >= DIN - p) { q -= (DIN - p); p++; }
            q += p;
            float acc = 0.f;
            for (int rr = 0; rr < 256; rr++) acc += L[rr][p] * L[rr][q];
            atomicAdd(&stats[p * DIN + q], acc);
            if (p != q) atomicAdd(&stats[q * DIN + p], acc);
        } else if (t < 230) {
            int k = t - 210;
            float acc = 0.f;
            for (int rr = 0; rr < 256; rr++) acc += L[rr][k];
            atomicAdd(&stats[400 + k], acc);
        }
        return;
    }
    if (bid < SB + A2B) {
        // ---- kA2 role: LDS counting sort by bucket, runs appended at
        //      b*CAP + atomicAdd(fill[b]) (contiguous-run global writes) ----
        u64* ldsE = (u64*)sm;                    // 2048*8 = 16384
        u64* ldsS = ldsE + EB2;                  // 16384
        u32* cntA = (u32*)(ldsS + EB2);          // 2048
        u32* cntB = cntA + 512;                  // 2048
        u32* offL = cntB + 512;                  // 2048
        u32* wsum4 = offL + 512;                 // 16
        u32* gbase = wsum4 + 4;                  // 1600
        for (int i = t; i < 512; i += 256) { cntA[i] = 0; cntB[i] = 0; }
        __syncthreads();
        int T1 = E1 + L1, T = T1 + E2 + L2;
        int base = (bid - SB) * EB2;
        int nE = T - base; if (nE > EB2) nE = EB2;
        for (int j = t; j < nE; j += 256) {
            int s, key;
            edge_at(base + j, src1, dst1, src2, dst2, E1, T1, E2, NR, s, key);
            ldsE[j] = ((u64)(u32)key << 32) | (u32)s;
            atomicAdd(&cntA[key >> 9], 1u);
        }
        __syncthreads();
        scan512f(cntA, offL, wsum4);
        for (int b = t; b < NB; b += 256) {
            u32 c = cntA[b];
            gbase[b] = c ? (((u32)b << CAPSH) + atomicAdd(&bucketFill[b], c)) : 0u;
        }
        __syncthreads();
        for (int j = t; j < nE; j += 256) {
            u64 e = ldsE[j];
            u32 b = ((u32)(e >> 32)) >> 9;
            u32 r = atomicAdd(&cntB[b], 1u);
            ldsS[offL[b] + r] = e;
        }
        __syncthreads();
        for (int j = t; j < nE; j += 256) {
            u64 e = ldsS[j];
            u32 b = ((u32)(e >> 32)) >> 9;
            pairs[gbase[b] + ((u32)j - offL[b])] = e;
        }
        return;
    }
    if (bid < SB + A2B + 32) {
        // ---- B-pack role (32 blocks) ----
        int idx0 = ((bid - SB - A2B) * 256 + t) * 4;
        #pragma unroll
        for (int i = 0; i < 4; i++) {
            int flat = idx0 + i;           // [nt(16)][kb(4)][lane(64)][j(8)]
            int j = flat & 7;
            int lane = (flat >> 3) & 63;
            int kb = (flat >> 9) & 3;
            int nt = flat >> 11;
            int k = kb * 32 + (lane >> 4) * 8 + j;
            int n = nt * 16 + (lane & 15);
            wsp[flat] = f2bf_rne(g2_ws[k * HC + n]);
        }
        return;
    }
    // ---- attention dot role (4 blocks): stats[676/932/1200/1456 + t] ------------
    // dr0: vd1=g1_wd·g1_ad  dr1: vd2=g2_wd·g2_ad  dr2: u1=g1_ws·g1_as  dr3: u2=g2_ws·g2_as
    int dr = bid - SB - A2B - 32;
    const float* wm = (dr == 0) ? g1_wd : (dr == 1) ? g2_wd : (dr == 2) ? g1_ws : g2_ws;
    const float* am = (dr == 0) ? g1_ad : (dr == 1) ? g2_ad : (dr == 2) ? g1_as : g2_as;
    int obase = (dr == 0) ? 676 : (dr == 1) ? 932 : (dr == 2) ? 1200 : 1456;
    {
        int k = t >> 1, h = t & 1;
        const float4* wp = (const float4*)(wm + k * HC + h * C);
        const float4* ap = (const float4*)(am + h * C);
        float acc = 0.f;
        #pragma unroll 4
        for (int q = 0; q < 32; q++) {
            float4 xv = wp[q], yv = ap[q];
            acc += xv.x * yv.x + xv.y * yv.y + xv.z * yv.z + xv.w * yv.w;
        }
        stats[obase + t] = acc;
    }
}

// ---------------- L2: precomp (single block; BN fold + T + cb + fv) ---------------
__global__ __launch_bounds__(256) void k_pre(float* __restrict__ stats,
    const float* __restrict__ W,
    const float* __restrict__ gamma, const float* __restrict__ beta,
    const float* __restrict__ g1_ws, const float* __restrict__ g1b, float invN)
{
    int t = threadIdx.x;
    __shared__ float Sm[420];
    __shared__ float Wm[DIN * C];
    __shared__ float vd1s[256];
    __shared__ float vd2s[256];
    __shared__ float sS[128];
    __shared__ float sSh[128];
    for (int i = t; i < 420; i += 256) Sm[i] = stats[i];
    for (int i = t; i < DIN * C; i += 256) Wm[i] = W[i];
    vd1s[t] = stats[676 + t];
    vd2s[t] = stats[932 + t];
    __syncthreads();
    if (t < C) {
        float w[DIN];
        #pragma unroll
        for (int k = 0; k < DIN; k++) w[k] = Wm[k * C + t];
        float mb = 0.f;
        #pragma unroll
        for (int k = 0; k < DIN; k++) mb += Sm[400 + k] * invN * w[k];
        float e2 = 0.f;
        for (int p = 0; p < DIN; p++) {
            float acc2 = 0.f;
            #pragma unroll
            for (int q = 0; q < DIN; q++) acc2 += Sm[p * DIN + q] * w[q];
            e2 += w[p] * acc2;
        }
        e2 *= invN;
        float var = e2 - mb * mb;
        float s = gamma[t] * rsqrtf(var + 1e-5f);
        float sh = beta[t] - s * mb;   // b_rl cancels inside BN
        stats[420 + t] = s;
        stats[548 + t] = sh;
        sS[t] = s;
        sSh[t] = sh;
    }
    {
        int k = t >> 1, h = t & 1;
        const float4* ws1p = (const float4*)(g1_ws + k * HC + h * C);
        float t0 = 0.f, t1 = 0.f;
        #pragma unroll 4
        for (int q = 0; q < 32; q++) {
            float4 wv = ws1p[q];
            int c = q * 4;
            t0 += wv.x * vd2s[(c + 0) * 2 + 0] + wv.y * vd2s[(c + 1) * 2 + 0]
                + wv.z * vd2s[(c + 2) * 2 + 0] + wv.w * vd2s[(c + 3) * 2 + 0];
            t1 += wv.x * vd2s[(c + 0) * 2 + 1] + wv.y * vd2s[(c + 1) * 2 + 1]
                + wv.z * vd2s[(c + 2) * 2 + 1] + wv.w * vd2s[(c + 3) * 2 + 1];
        }
        stats[1712 + t * 2 + 0] = t0;
        stats[1712 + t * 2 + 1] = t1;
    }
    if (t < 2) {
        float cb = 0.f;
        for (int k = 0; k < C; k++) cb += g1b[k] * vd2s[k * 2 + t];
        stats[1188 + t] = cb;
    }
    __syncthreads();
    if (t < 80) {
        int k = t >> 2, h4 = t & 3, h = h4 & 1;
        const float* vs = (h4 < 2) ? vd1s : vd2s;
        float acc = 0.f;
        for (int c = 0; c < C; c++) acc += sS[c] * Wm[k * C + c] * vs[c * 2 + h];
        stats[2240 + t] = acc;
    } else if (t < 84) {
        int h4 = t - 80, h = h4 & 1;
        const float* vs = (h4 < 2) ? vd1s : vd2s;
        float acc = 0.f;
        for (int c = 0; c < C; c++) acc += sSh[c] * vs[c * 2 + h];
        stats[2320 + h4] = acc;
    }
}

// ---------------- L3: kB fine sort ∥ r0f GEMV ∥ ing psi ∥ user hs MFMA ------------
// blocks [0,NB): kB -> off2/sorted; [NB,+R0B): r0f; [+IB): ing; [+HB): hs
__global__ __launch_bounds__(256) void k_fin(const u64* __restrict__ pairs,
    const u32* __restrict__ bucketFill, int n2, int NB, int R0B, int IB,
    int* __restrict__ off2, int* __restrict__ sorted,
    const float* __restrict__ x, int NR, const float* __restrict__ stats,
    float* __restrict__ a_d, float* __restrict__ advd,
    const float* __restrict__ ing_table, const int* __restrict__ ing_ids, int NI,
    float* __restrict__ a_si, float* __restrict__ psi,
    const float* __restrict__ user_table, const int* __restrict__ user_ids, int NU,
    const u16* __restrict__ wsp, u16* __restrict__ hs16, float* __restrict__ a_su)
{
    __shared__ __align__(16) char sm[30736];
    int t = threadIdx.x;
    int bid = blockIdx.x;
    if (bid < NB) {
        u32* cntA = (u32*)sm;          // 2048
        u32* cntB = cntA + 512;        // 2048
        u32* offL = cntB + 512;        // 2048
        u32* wsum4 = offL + 512;       // 16
        u32* ldsS = wsum4 + 4;         // 6144*4 = 24576
        int b = bid;
        u32 beg = (u32)b << CAPSH;
        u32 fill = bucketFill[b];
        u32 end = beg + fill;
        int dstBase = b << 9;
        for (int i = t; i < 512; i += 256) { cntA[i] = 0; cntB[i] = 0; }
        __syncthreads();
        for (u32 j = beg + t; j < end; j += 256) {
            u32 key = (u32)(pairs[j] >> 32);
            atomicAdd(&cntA[key - dstBase], 1u);
        }
        __syncthreads();
        scan512f(cntA, offL, wsum4);
        for (int d = t; d < 512; d += 256) {
            int gk = dstBase + d;
            if (gk < n2) {
                int s0 = (int)(beg + offL[d]);
                off2[2 * gk] = s0;
                off2[2 * gk + 1] = s0 + (int)cntA[d];
            }
        }
        bool fast = fill <= 6144u;
        __syncthreads();
        for (u32 j = beg + t; j < end; j += 256) {
            u64 e = pairs[j];
            u32 d = (u32)(e >> 32) - dstBase;
            u32 r = atomicAdd(&cntB[d], 1u);
            u32 pos = offL[d] + r;
            if (fast) ldsS[pos] = (u32)e;
            else sorted[beg + pos] = (int)(u32)e;
        }
        __syncthreads();
        if (fast) {
            for (u32 j = t; j < fill; j += 256) sorted[beg + j] = (int)ldsS[j];
        }
        return;
    }
    if (bid < NB + R0B) {
        // ---- r0f GEMV role ----
        float* fv = (float*)sm;
        if (t < 84) fv[t] = stats[2240 + t];
        __syncthreads();
        int r = (bid - NB) * 256 + t;
        if (r < NR) {
            const float4* xp = (const float4*)(x + (size_t)r * DIN);
            float4 v0 = xp[0], v1 = xp[1], v2 = xp[2], v3 = xp[3], v4 = xp[4];
            float xv[20] = {v0.x, v0.y, v0.z, v0.w, v1.x, v1.y, v1.z, v1.w,
                            v2.x, v2.y, v2.z, v2.w, v3.x, v3.y, v3.z, v3.w,
                            v4.x, v4.y, v4.z, v4.w};
            float a0 = 0.f, a1 = 0.f, b0 = 0.f, b1 = 0.f;
            #pragma unroll
            for (int k = 0; k < DIN; k++) {
                float xvk = xv[k];
                a0 += xvk * fv[k * 4 + 0];
                a1 += xvk * fv[k * 4 + 1];
                b0 += xvk * fv[k * 4 + 2];
                b1 += xvk * fv[k * 4 + 3];
            }
            ((float2*)a_d)[r]  = make_float2(a0 + fv[80], a1 + fv[81]);
            ((float2*)advd)[r] = make_float2(b0 + fv[82], b1 + fv[83]);
        }
        return;
    }
    if (bid < NB + R0B + IB) {
        // ---- ingredient role ----
        float* u1s = (float*)sm;
        float* Ts  = u1s + 256;
        u1s[t] = stats[1200 + t];
        Ts[t] = stats[1712 + t];
        Ts[256 + t] = stats[1968 + t];
        __syncthreads();
        int r = t >> 3, cg = t & 7;
        int row = (bid - NB - R0B) * 32 + r;
        float as0 = 0.f, as1 = 0.f, p00 = 0.f, p01 = 0.f, p10 = 0.f, p11 = 0.f;
        if (row < NI) {
            const float* xp = ing_table + (size_t)ing_ids[row] * C + cg * 16;
            #pragma unroll
            for (int q = 0; q < 4; q++) {
                float4 v = ((const float4*)xp)[q];
                float xvv[4] = {v.x, v.y, v.z, v.w};
                #pragma unroll
                for (int jj = 0; jj < 4; jj++) {
                    int k = cg * 16 + q * 4 + jj;
                    float xx = xvv[jj];
                    as0 += xx * u1s[k * 2 + 0];
                    as1 += xx * u1s[k * 2 + 1];
                    p00 += xx * Ts[k * 4 + 0];
                    p01 += xx * Ts[k * 4 + 1];
                    p10 += xx * Ts[k * 4 + 2];
                    p11 += xx * Ts[k * 4 + 3];
                }
            }
        }
        #pragma unroll
        for (int m = 1; m <= 4; m <<= 1) {
            as0 += __shfl_xor(as0, m); as1 += __shfl_xor(as1, m);
            p00 += __shfl_xor(p00, m); p01 += __shfl_xor(p01, m);
            p10 += __shfl_xor(p10, m); p11 += __shfl_xor(p11, m);
        }
        if (cg == 0 && row < NI) {
            ((float2*)a_si)[row] = make_float2(as0, as1);
            float4 pv; pv.x = p00; pv.y = p01; pv.z = p10; pv.w = p11;
            ((float4*)psi)[row] = pv;
        }
        return;
    }
    // ---- user hs MFMA role ----
    u16* A = (u16*)sm;                       // 32*136*2 = 8704 B
    float* u2s = (float*)(sm + 8704);        // 1024 B
    u2s[t] = stats[1456 + t];
    int rowBase = (bid - NB - R0B - IB) * 32;
    int r = t >> 3, cg = t & 7;
    int row = rowBase + r;
    float xv[16];
    if (row < NU) {
        const float* xp = user_table + (size_t)user_ids[row] * C + cg * 16;
        #pragma unroll
        for (int q = 0; q < 4; q++) {
            float4 v = ((const float4*)xp)[q];
            xv[q * 4 + 0] = v.x; xv[q * 4 + 1] = v.y;
            xv[q * 4 + 2] = v.z; xv[q * 4 + 3] = v.w;
        }
    } else {
        #pragma unroll
        for (int q = 0; q < 16; q++) xv[q] = 0.f;
    }
    float ss = 0.f;
    #pragma unroll
    for (int q = 0; q < 16; q++) ss += xv[q] * xv[q];
    #pragma unroll
    for (int m = 1; m <= 4; m <<= 1) ss += __shfl_xor(ss, m);
    float nn = sqrtf(ss);
    float f = (nn > 1.f) ? 1.f / (nn + 1e-7f) : 1.f;
    float as0 = 0.f, as1 = 0.f;
    #pragma unroll
    for (int q = 0; q < 16; q++) {
        xv[q] *= f;
        int k = cg * 16 + q;
        as0 += xv[q] * u2s[k * 2 + 0];
        as1 += xv[q] * u2s[k * 2 + 1];
    }
    #pragma unroll
    for (int m = 1; m <= 4; m <<= 1) {
        as0 += __shfl_xor(as0, m); as1 += __shfl_xor(as1, m);
    }
    if (cg == 0 && row < NU) ((float2*)a_su)[row] = make_float2(as0, as1);
    {
        union { u16 h[16]; uint4 u4[2]; } pk;
        #pragma unroll
        for (int q = 0; q < 16; q++) pk.h[q] = f2bf_rne(xv[q]);
        uint4* dst = (uint4*)&A[r * 136 + cg * 16];
        dst[0] = pk.u4[0];
        dst[1] = pk.u4[1];
    }
    __syncthreads();
    int w = t >> 6, l = t & 63;
    int m15 = l & 15, q4 = l >> 4;
    bf16x8 afrag[2][4];
    #pragma unroll
    for (int mt = 0; mt < 2; mt++)
        #pragma unroll
        for (int kb = 0; kb < 4; kb++)
            afrag[mt][kb] = *(const bf16x8*)&A[(mt * 16 + m15) * 136 + kb * 32 + q4 * 8];
    f32x4 acc[2][4];
    #pragma unroll
    for (int mt = 0; mt < 2; mt++)
        #pragma unroll
        for (int i = 0; i < 4; i++) acc[mt][i] = (f32x4){0.f, 0.f, 0.f, 0.f};
    #pragma unroll
    for (int kb = 0; kb < 4; kb++) {
        #pragma unroll
        for (int i = 0; i < 4; i++) {
            int nt = w * 4 + i;
            bf16x8 bfrag = *(const bf16x8*)&wsp[((nt * 4 + kb) * 64 + l) * 8];
            acc[0][i] = __builtin_amdgcn_mfma_f32_16x16x32_bf16(afrag[0][kb], bfrag, acc[0][i], 0, 0, 0);
            acc[1][i] = __builtin_amdgcn_mfma_f32_16x16x32_bf16(afrag[1][kb], bfrag, acc[1][i], 0, 0, 0);
        }
    }
    #pragma unroll
    for (int mt = 0; mt < 2; mt++) {
        #pragma unroll
        for (int i = 0; i < 4; i++) {
            int col = (w * 4 + i) * 16 + m15;
            #pragma unroll
            for (int rr = 0; rr < 4; rr++) {
                int rw = rowBase + mt * 16 + q4 * 4 + rr;
                if (rw < NU) hs16[(size_t)rw * HC + col] = f2bf_rne(acc[mt][i][rr]);
            }
        }
    }
}

// ---------------- L4: fused GAT1 (psi) then GAT2 (R4 uint2 gather) ----------------
__global__ __launch_bounds__(256) void k_agg(const int* __restrict__ off2, const int* __restrict__ sorted,
    const float* __restrict__ a_si, const float* __restrict__ psi,
    const float* __restrict__ a_d1, const float* __restrict__ advd,
    const float* __restrict__ cb,
    const float* __restrict__ a_su, const u16* __restrict__ hs16,
    const float* __restrict__ bias, int NR, float* __restrict__ out)
{
    int wave = threadIdx.x >> 6, lane = threadIdx.x & 63;
    int d = blockIdx.x * 4 + wave;
    if (d >= NR) return;
    // ---------- phase 1: GAT1 psi aggregation ----------
    int beg = off2[2 * d], end = off2[2 * d + 1];
    float ad0 = a_d1[d * 2 + 0], ad1 = a_d1[d * 2 + 1];
    float w0s = 0.f, w1s = 0.f, a00 = 0.f, a01 = 0.f, a10 = 0.f, a11 = 0.f;
    for (int j = beg + lane; j < end; j += 64) {
        int s = sorted[j];
        float2 as = ((const float2*)a_si)[s];
        float e0 = as.x + ad0; e0 = (e0 >= 0.f) ? e0 : 0.2f * e0;
        float e1 = as.y + ad1; e1 = (e1 >= 0.f) ? e1 : 0.2f * e1;
        float x0 = __expf(e0), x1 = __expf(e1);
        float4 p = ((const float4*)psi)[s];
        w0s += x0; w1s += x1;
        a00 += x0 * p.x; a01 += x0 * p.y;
        a10 += x1 * p.z; a11 += x1 * p.w;
    }
    #pragma unroll
    for (int o = 1; o < 64; o <<= 1) {
        w0s += __shfl_xor(w0s, o); w1s += __shfl_xor(w1s, o);
        a00 += __shfl_xor(a00, o); a01 += __shfl_xor(a01, o);
        a10 += __shfl_xor(a10, o); a11 += __shfl_xor(a11, o);
    }
    float inv0g = 1.f / (w0s + 1e-16f), inv1g = 1.f / (w1s + 1e-16f);
    float r0 = advd[d * 2 + 0] + cb[0] + 0.5f * (a00 * inv0g + a10 * inv1g);
    float r1 = advd[d * 2 + 1] + cb[1] + 0.5f * (a01 * inv0g + a11 * inv1g);
    // ---------- phase 2: GAT2 hs16 row gather (R4 uint2 1-edge/step) ----------
    int i2 = NR + d;
    int beg2 = off2[2 * i2], end2 = off2[2 * i2 + 1];
    int head = lane >> 5;
    int q = lane & 31;
    u32 laneoff = (u32)(head * 256 + q * 8);
    int hsel = lane & 32;
    float adh = head ? r1 : r0;
    float wsum = 0.f;
    float acc0 = 0.f, acc1 = 0.f, acc2 = 0.f, acc3 = 0.f;
    const char* hbase = (const char*)hs16;

    for (int base = beg2; base < end2; base += 32) {
        int rem = end2 - base; if (rem > 32) rem = 32;
        int j = q; if (j >= rem) j = rem - 1;
        int sp = sorted[base + j];
        u32 boff = ((u32)sp) << 9;
        float asv = a_su[sp * 2 + head];
        float ee = asv + adh; ee = (ee >= 0.f) ? ee : 0.2f * ee;
        float wcomb = __expf(ee);
        int e = 0;
        for (; e + 4 <= rem; e += 4) {
            u32 b0 = __shfl(boff, e + 0), b1 = __shfl(boff, e + 1);
            u32 b2 = __shfl(boff, e + 2), b3 = __shfl(boff, e + 3);
            uint2 g0 = *(const uint2*)(hbase + (b0 + laneoff));
            uint2 g1 = *(const uint2*)(hbase + (b1 + laneoff));
            uint2 g2 = *(const uint2*)(hbase + (b2 + laneoff));
            uint2 g3 = *(const uint2*)(hbase + (b3 + laneoff));
            float W0 = __shfl(wcomb, hsel + e + 0);
            float W1 = __shfl(wcomb, hsel + e + 1);
            float W2 = __shfl(wcomb, hsel + e + 2);
            float W3 = __shfl(wcomb, hsel + e + 3);
            wsum += (W0 + W1) + (W2 + W3);
            acc0 += W0 * bfbits2f(g0.x & 0xFFFFu);
            acc1 += W0 * __uint_as_float(g0.x & 0xFFFF0000u);
            acc2 += W0 * bfbits2f(g0.y & 0xFFFFu);
            acc3 += W0 * __uint_as_float(g0.y & 0xFFFF0000u);
            acc0 += W1 * bfbits2f(g1.x & 0xFFFFu);
            acc1 += W1 * __uint_as_float(g1.x & 0xFFFF0000u);
            acc2 += W1 * bfbits2f(g1.y & 0xFFFFu);
            acc3 += W1 * __uint_as_float(g1.y & 0xFFFF0000u);
            acc0 += W2 * bfbits2f(g2.x & 0xFFFFu);
            acc1 += W2 * __uint_as_float(g2.x & 0xFFFF0000u);
            acc2 += W2 * bfbits2f(g2.y & 0xFFFFu);
            acc3 += W2 * __uint_as_float(g2.y & 0xFFFF0000u);
            acc0 += W3 * bfbits2f(g3.x & 0xFFFFu);
            acc1 += W3 * __uint_as_float(g3.x & 0xFFFF0000u);
            acc2 += W3 * bfbits2f(g3.y & 0xFFFFu);
            acc3 += W3 * __uint_as_float(g3.y & 0xFFFF0000u);
        }
        for (; e < rem; e++) {
            u32 b0 = __shfl(boff, e);
            float W = __shfl(wcomb, hsel + e);
            uint2 g = *(const uint2*)(hbase + (b0 + laneoff));
            wsum += W;
            acc0 += W * bfbits2f(g.x & 0xFFFFu);
            acc1 += W * __uint_as_float(g.x & 0xFFFF0000u);
            acc2 += W * bfbits2f(g.y & 0xFFFFu);
            acc3 += W * __uint_as_float(g.y & 0xFFFF0000u);
        }
    }
    float inv = 1.f / (wsum + 1e-16f);
    float v0 = acc0 * inv, v1 = acc1 * inv, v2 = acc2 * inv, v3 = acc3 * inv;
    v0 = 0.5f * (v0 + __shfl_xor(v0, 32));
    v1 = 0.5f * (v1 + __shfl_xor(v1, 32));
    v2 = 0.5f * (v2 + __shfl_xor(v2, 32));
    v3 = 0.5f * (v3 + __shfl_xor(v3, 32));
    if (lane < 32) {
        float4 bb = ((const float4*)bias)[q];
        float4 o;
        o.x = v0 + bb.x; o.y = v1 + bb.y; o.z = v2 + bb.z; o.w = v3 + bb.w;
        ((float4*)(out + (size_t)d * C))[q] = o;
    }
}

extern "C" void kernel_launch(void* const* d_in, const int* in_sizes, int n_in,
                              void* d_out, int out_size, void* d_ws, size_t ws_size,
                              hipStream_t stream) {
    const int*   user_ids       = (const int*)d_in[0];
    const int*   ingredient_ids = (const int*)d_in[1];
    const float* recipe_x       = (const float*)d_in[2];
    const int*   ing_src        = (const int*)d_in[3];
    const int*   ing_dst        = (const int*)d_in[4];
    const int*   ub_src         = (const int*)d_in[5];
    const int*   ub_dst         = (const int*)d_in[6];
    const float* user_table     = (const float*)d_in[7];
    const float* ing_table      = (const float*)d_in[8];
    const float* W_rl           = (const float*)d_in[9];
    const float* bn_gamma       = (const float*)d_in[11];
    const float* bn_beta        = (const float*)d_in[12];
    const float* g1_ws          = (const float*)d_in[13];
    const float* g1_wd          = (const float*)d_in[14];
    const float* g1_as          = (const float*)d_in[15];
    const float* g1_ad          = (const float*)d_in[16];
    const float* g1_b           = (const float*)d_in[17];
    const float* g2_ws          = (const float*)d_in[18];
    const float* g2_wd          = (const float*)d_in[19];
    const float* g2_as          = (const float*)d_in[20];
    const float* g2_ad          = (const float*)d_in[21];
    const float* g2_b           = (const float*)d_in[22];

    int NU = in_sizes[0];
    int NI = in_sizes[1];
    int NR = in_sizes[2] / DIN;
    int E1 = in_sizes[3];
    int E2 = in_sizes[5];
    int Nmax = (NI > NU) ? NI : NU;
    int L1 = (NI < NR) ? NI : NR;
    int L2 = (NU < NR) ? NU : NR;
    int Etot = E1 + L1 + E2 + L2;
    int n2 = 2 * NR;
    int NB = (n2 + 511) >> 9;

    char* w = (char*)d_ws;
    u16*   hs16  = (u16*)w;    w += (size_t)Nmax * HC * 2;
    float* a_si  = (float*)w;  w += (size_t)NI * 2 * 4;
    float* a_su  = (float*)w;  w += (size_t)NU * 2 * 4;
    float* psi   = (float*)w;  w += (size_t)NI * 4 * 4;
    float* a_d   = (float*)w;  w += (size_t)NR * 2 * 4;
    float* advd  = (float*)w;  w += (size_t)NR * 2 * 4;
    float* stats = (float*)w;  w += 2432 * 4;
    u32*   bucketFill = (u32*)w; w += MAXNB * 4;     // adjacent to stats: one memset
    u16*   wsp   = (u16*)w;    w += 32768 * 2;
    int*   off2  = (int*)w;    w += (size_t)(2 * n2) * 4;
    int*   sorted= (int*)w;    w += (size_t)NB * CAP * 4;
    w = (char*)(((size_t)w + 15) & ~(size_t)15);
    u64*   pairs = (u64*)w;    w += (size_t)NB * CAP * 8;

    hipMemsetAsync(stats, 0, (2432 + MAXNB) * 4, stream);

    int SB  = (NR + 255) / 256;
    int A2B = (Etot + EB2 - 1) / EB2;
    // L1: BN stats ∥ kA2 bucket sort ∥ B-pack ∥ attention dots
    k_init<<<SB + A2B + 32 + 4, 256, 0, stream>>>(recipe_x, NR, stats, SB, A2B,
                                              ing_src, ing_dst, ub_src, ub_dst,
                                              E1, L1, E2, L2, NB,
                                              bucketFill, pairs, g2_ws, wsp,
                                              g1_wd, g1_ad, g2_wd, g2_ad,
                                              g1_ws, g1_as, g2_as);
    // L2: precomp (1 block: BN fold + T + cb + fv)
    k_pre<<<1, 256, 0, stream>>>(stats, W_rl, bn_gamma, bn_beta,
                                 g1_ws, g1_b, 1.0f / NR);
    // L3: kB fine sort ∥ r0f GEMV ∥ ingredient psi ∥ user hs MFMA
    int R0B = (NR + 255) / 256;
    int IB  = (NI + 31) / 32;
    int HB  = (NU + 31) / 32;
    k_fin<<<NB + R0B + IB + HB, 256, 0, stream>>>(pairs, bucketFill, n2, NB, R0B, IB,
                                                  off2, sorted,
                                                  recipe_x, NR, stats, a_d, advd,
                                                  ing_table, ingredient_ids, NI, a_si, psi,
                                                  user_table, user_ids, NU,
                                                  wsp, hs16, a_su);
    // L4: fused GAT1 + GAT2 aggregation
    k_agg<<<(NR + 3) / 4, 256, 0, stream>>>(off2, sorted, a_si, psi, a_d, advd,
                                            stats + 1188, a_su, hs16, g2_b, NR,
                                            (float*)d_out);
}

// Round 10
// 292.093 us; speedup vs baseline: 1.2295x; 1.0296x over previous
//
#include <hip/hip_runtime.h>
#include <hip/hip_bf16.h>
#include <math.h>

#define DIN 20
#define C 128
#define HC 256
#define EB2 2048
#define MAXNB 400
#define CAP 8192
#define CAPSH 13

typedef unsigned short u16;
typedef unsigned int u32;
typedef unsigned long long u64;
typedef __bf16 bf16x8 __attribute__((ext_vector_type(8)));
typedef float f32x4 __attribute__((ext_vector_type(4)));

__device__ __forceinline__ float bfbits2f(unsigned int lo16) {
    return __uint_as_float(lo16 << 16);
}
__device__ __forceinline__ u16 f2bf_rne(float f) {
    unsigned int b = __float_as_uint(f);
    return (u16)((b + 0x7FFFu + ((b >> 16) & 1u)) >> 16);
}

// exclusive scan of cnt[0..511] -> off[0..511]; wave-shuffle scan, 2 barriers
__device__ __forceinline__ void scan512f(u32* cnt, u32* off, u32* wsum4) {
    int t = threadIdx.x;
    int l = t & 63, w = t >> 6;
    u32 a = cnt[2 * t], b = cnt[2 * t + 1];
    u32 s = a + b;
    u32 isc = s;
    #pragma unroll
    for (int o = 1; o < 64; o <<= 1) {
        u32 n = __shfl_up(isc, o);
        if (l >= o) isc += n;
    }
    if (l == 63) wsum4[w] = isc;
    __syncthreads();
    u32 pre = 0;
    if (w > 0) pre += wsum4[0];
    if (w > 1) pre += wsum4[1];
    if (w > 2) pre += wsum4[2];
    u32 excl = pre + isc - s;
    off[2 * t] = excl;
    off[2 * t + 1] = excl + a;
    __syncthreads();
}

__device__ __forceinline__ void edge_at(int i, const int* s1, const int* d1,
    const int* s2, const int* d2, int E1, int T1, int E2, int NR,
    int& s, int& key)
{
    if (i < T1) {
        if (i < E1) { s = s1[i]; key = d1[i]; }
        else        { s = i - E1; key = i - E1; }
    } else {
        int k = i - T1;
        if (k < E2) { s = s2[k]; key = NR + d2[k]; }
        else        { s = k - E2; key = NR + (k - E2); }
    }
}

// ---- L1: BN stats ∥ kA2 bucket-sort (u32 pairs) ∥ B-pack ∥ dots (+T,+cb) --------
// blocks [0,SB): BN; [SB,+A2B): kA2; [+32): pack; [+4): dots (dr1 also does T,cb)
__global__ __launch_bounds__(256) void k_init(const float* __restrict__ x, int NR,
    float* __restrict__ stats, int SB, int A2B,
    const int* __restrict__ src1, const int* __restrict__ dst1,
    const int* __restrict__ src2, const int* __restrict__ dst2,
    int E1, int L1, int E2, int L2, int NB,
    u32* __restrict__ bucketFill, u32* __restrict__ pairs,
    const float* __restrict__ g2_ws, u16* __restrict__ wsp,
    const float* __restrict__ g1_wd, const float* __restrict__ g1_ad,
    const float* __restrict__ g2_wd, const float* __restrict__ g2_ad,
    const float* __restrict__ g1_ws, const float* __restrict__ g1_as,
    const float* __restrict__ g2_as, const float* __restrict__ g1b)
{
    __shared__ __align__(16) char sm[40528];
    int t = threadIdx.x;
    int bid = blockIdx.x;
    if (bid < SB) {
        // ---- BN stats role (vectorized row load) ----
        float (*L)[DIN] = (float(*)[DIN])sm;
        int r = bid * 256 + t;
        if (r < NR) {
            const float4* xp = (const float4*)(x + (size_t)r * DIN);
            float4 v0 = xp[0], v1 = xp[1], v2 = xp[2], v3 = xp[3], v4 = xp[4];
            L[t][0] = v0.x; L[t][1] = v0.y; L[t][2] = v0.z; L[t][3] = v0.w;
            L[t][4] = v1.x; L[t][5] = v1.y; L[t][6] = v1.z; L[t][7] = v1.w;
            L[t][8] = v2.x; L[t][9] = v2.y; L[t][10] = v2.z; L[t][11] = v2.w;
            L[t][12] = v3.x; L[t][13] = v3.y; L[t][14] = v3.z; L[t][15] = v3.w;
            L[t][16] = v4.x; L[t][17] = v4.y; L[t][18] = v4.z; L[t][19] = v4.w;
        } else {
            #pragma unroll
            for (int k = 0; k < DIN; k++) L[t][k] = 0.f;
        }
        __syncthreads();
        if (t < 210) {
            int p = 0, q = t;
            while (q >= DIN - p) { q -= (DIN - p); p++; }
            q += p;
            float acc = 0.f;
            for (int rr = 0; rr < 256; rr++) acc += L[rr][p] * L[rr][q];
            atomicAdd(&stats[p * DIN + q], acc);
            if (p != q) atomicAdd(&stats[q * DIN + p], acc);
        } else if (t < 230) {
            int k = t - 210;
            float acc = 0.f;
            for (int rr = 0; rr < 256; rr++) acc += L[rr][k];
            atomicAdd(&stats[400 + k], acc);
        }
        return;
    }
    if (bid < SB + A2B) {
        // ---- kA2 role: LDS counting sort by bucket; u32 packed global writes ----
        u64* ldsE = (u64*)sm;                    // 2048*8 = 16384
        u64* ldsS = ldsE + EB2;                  // 16384
        u32* cntA = (u32*)(ldsS + EB2);          // 2048
        u32* cntB = cntA + 512;                  // 2048
        u32* offL = cntB + 512;                  // 2048
        u32* wsum4 = offL + 512;                 // 16
        u32* gbase = wsum4 + 4;                  // 1600
        for (int i = t; i < 512; i += 256) { cntA[i] = 0; cntB[i] = 0; }
        __syncthreads();
        int T1 = E1 + L1, T = T1 + E2 + L2;
        int base = (bid - SB) * EB2;
        int nE = T - base; if (nE > EB2) nE = EB2;
        for (int j = t; j < nE; j += 256) {
            int s, key;
            edge_at(base + j, src1, dst1, src2, dst2, E1, T1, E2, NR, s, key);
            ldsE[j] = ((u64)(u32)key << 32) | (u32)s;
            atomicAdd(&cntA[key >> 9], 1u);
        }
        __syncthreads();
        scan512f(cntA, offL, wsum4);
        for (int b = t; b < NB; b += 256) {
            u32 c = cntA[b];
            gbase[b] = c ? (((u32)b << CAPSH) + atomicAdd(&bucketFill[b], c)) : 0u;
        }
        __syncthreads();
        for (int j = t; j < nE; j += 256) {
            u64 e = ldsE[j];
            u32 b = ((u32)(e >> 32)) >> 9;
            u32 r = atomicAdd(&cntB[b], 1u);
            ldsS[offL[b] + r] = e;
        }
        __syncthreads();
        for (int j = t; j < nE; j += 256) {
            u64 e = ldsS[j];
            u32 key = (u32)(e >> 32);
            u32 b = key >> 9;
            // pack: fine(9b) << 17 | src(17b) -- src < 2^17 for this problem
            pairs[gbase[b] + ((u32)j - offL[b])] = ((key & 511u) << 17) | (u32)e;
        }
        return;
    }
    if (bid < SB + A2B + 32) {
        // ---- B-pack role (32 blocks) ----
        int idx0 = ((bid - SB - A2B) * 256 + t) * 4;
        #pragma unroll
        for (int i = 0; i < 4; i++) {
            int flat = idx0 + i;           // [nt(16)][kb(4)][lane(64)][j(8)]
            int j = flat & 7;
            int lane = (flat >> 3) & 63;
            int kb = (flat >> 9) & 3;
            int nt = flat >> 11;
            int k = kb * 32 + (lane >> 4) * 8 + j;
            int n = nt * 16 + (lane & 15);
            wsp[flat] = f2bf_rne(g2_ws[k * HC + n]);
        }
        return;
    }
    // ---- attention dot role (4 blocks) ----
    // dr0: vd1=g1_wd·g1_ad  dr1: vd2=g2_wd·g2_ad (+T,+cb)  dr2: u1  dr3: u2
    int dr = bid - SB - A2B - 32;
    const float* wm = (dr == 0) ? g1_wd : (dr == 1) ? g2_wd : (dr == 2) ? g1_ws : g2_ws;
    const float* am = (dr == 0) ? g1_ad : (dr == 1) ? g2_ad : (dr == 2) ? g1_as : g2_as;
    int obase = (dr == 0) ? 676 : (dr == 1) ? 932 : (dr == 2) ? 1200 : 1456;
    float* vd2l = (float*)sm;
    float acc = 0.f;
    {
        int k = t >> 1, h = t & 1;
        const float4* wp = (const float4*)(wm + k * HC + h * C);
        const float4* ap = (const float4*)(am + h * C);
        #pragma unroll 4
        for (int q = 0; q < 32; q++) {
            float4 xv = wp[q], yv = ap[q];
            acc += xv.x * yv.x + xv.y * yv.y + xv.z * yv.z + xv.w * yv.w;
        }
        stats[obase + t] = acc;
    }
    if (dr == 1) {
        vd2l[t] = acc;
        __syncthreads();
        // T[k*4+h*2+h'] = sum_c g1_ws[k][h*C+c] * vd2[c*2+h']
        int k = t >> 1, h = t & 1;
        const float4* ws1p = (const float4*)(g1_ws + k * HC + h * C);
        float t0 = 0.f, t1 = 0.f;
        #pragma unroll 4
        for (int q = 0; q < 32; q++) {
            float4 wv = ws1p[q];
            int c = q * 4;
            t0 += wv.x * vd2l[(c + 0) * 2 + 0] + wv.y * vd2l[(c + 1) * 2 + 0]
                + wv.z * vd2l[(c + 2) * 2 + 0] + wv.w * vd2l[(c + 3) * 2 + 0];
            t1 += wv.x * vd2l[(c + 0) * 2 + 1] + wv.y * vd2l[(c + 1) * 2 + 1]
                + wv.z * vd2l[(c + 2) * 2 + 1] + wv.w * vd2l[(c + 3) * 2 + 1];
        }
        stats[1712 + t * 2 + 0] = t0;
        stats[1712 + t * 2 + 1] = t1;
        if (t < 2) {
            float cb = 0.f;
            for (int k2 = 0; k2 < C; k2++) cb += g1b[k2] * vd2l[k2 * 2 + t];
            stats[1188 + t] = cb;
        }
    }
}

// ---------------- L2: kB fine sort ∥ r0f (inline BN fold+fv) ∥ ing ∥ user hs ------
// blocks [0,NB): kB -> off2/sorted; [NB,+R0B): r0f; [+IB): ing; [+HB): hs
__global__ __launch_bounds__(256) void k_fin(const u32* __restrict__ pairs,
    const u32* __restrict__ bucketFill, int n2, int NB, int R0B, int IB,
    int* __restrict__ off2, int* __restrict__ sorted,
    const float* __restrict__ x, int NR, const float* __restrict__ stats,
    const float* __restrict__ W, const float* __restrict__ gamma,
    const float* __restrict__ beta, float invN,
    float* __restrict__ a_d, float* __restrict__ advd,
    const float* __restrict__ ing_table, const int* __restrict__ ing_ids, int NI,
    float* __restrict__ a_si, float* __restrict__ psi,
    const float* __restrict__ user_table, const int* __restrict__ user_ids, int NU,
    const u16* __restrict__ wsp, u16* __restrict__ hs16, float* __restrict__ a_su)
{
    __shared__ __align__(16) char sm[30736];
    int t = threadIdx.x;
    int bid = blockIdx.x;
    if (bid < NB) {
        u32* cntA = (u32*)sm;          // 2048
        u32* cntB = cntA + 512;        // 2048
        u32* offL = cntB + 512;        // 2048
        u32* wsum4 = offL + 512;       // 16
        u32* ldsS = wsum4 + 4;         // 6144*4 = 24576
        int b = bid;
        u32 beg = (u32)b << CAPSH;
        u32 fill = bucketFill[b];
        u32 end = beg + fill;
        int dstBase = b << 9;
        for (int i = t; i < 512; i += 256) { cntA[i] = 0; cntB[i] = 0; }
        __syncthreads();
        for (u32 j = beg + t; j < end; j += 256) {
            u32 fine = pairs[j] >> 17;
            atomicAdd(&cntA[fine], 1u);
        }
        __syncthreads();
        scan512f(cntA, offL, wsum4);
        for (int d = t; d < 512; d += 256) {
            int gk = dstBase + d;
            if (gk < n2) {
                int s0 = (int)(beg + offL[d]);
                off2[2 * gk] = s0;
                off2[2 * gk + 1] = s0 + (int)cntA[d];
            }
        }
        bool fast = fill <= 6144u;
        __syncthreads();
        for (u32 j = beg + t; j < end; j += 256) {
            u32 p = pairs[j];
            u32 d = p >> 17;
            u32 r = atomicAdd(&cntB[d], 1u);
            u32 pos = offL[d] + r;
            u32 src = p & 0x1FFFFu;
            if (fast) ldsS[pos] = src;
            else sorted[beg + pos] = (int)src;
        }
        __syncthreads();
        if (fast) {
            for (u32 j = t; j < fill; j += 256) sorted[beg + j] = (int)ldsS[j];
        }
        return;
    }
    if (bid < NB + R0B) {
        // ---- r0f GEMV role with per-block inline BN fold + fv ----
        float* Sm   = (float*)sm;          // 420
        float* Wm   = Sm + 420;            // 2560
        float* vd1s = Wm + 2560;           // 256
        float* vd2s = vd1s + 256;          // 256
        float* sS   = vd2s + 256;          // 128
        float* sSh  = sS + 128;            // 128
        float* fv   = sSh + 128;           // 84  (total 4092 floats = 16368 B)
        for (int i = t; i < 420; i += 256) Sm[i] = stats[i];
        for (int i = t; i < DIN * C; i += 256) Wm[i] = W[i];
        vd1s[t] = stats[676 + t];
        vd2s[t] = stats[932 + t];
        __syncthreads();
        if (t < C) {
            float w[DIN];
            #pragma unroll
            for (int k = 0; k < DIN; k++) w[k] = Wm[k * C + t];
            float mb = 0.f;
            #pragma unroll
            for (int k = 0; k < DIN; k++) mb += Sm[400 + k] * invN * w[k];
            float e2 = 0.f;
            for (int p = 0; p < DIN; p++) {
                float acc2 = 0.f;
                #pragma unroll
                for (int q = 0; q < DIN; q++) acc2 += Sm[p * DIN + q] * w[q];
                e2 += w[p] * acc2;
            }
            e2 *= invN;
            float var = e2 - mb * mb;
            float s = gamma[t] * rsqrtf(var + 1e-5f);
            sS[t] = s;
            sSh[t] = beta[t] - s * mb;   // b_rl cancels inside BN
        }
        __syncthreads();
        if (t < 80) {
            int k = t >> 2, h4 = t & 3, h = h4 & 1;
            const float* vs = (h4 < 2) ? vd1s : vd2s;
            float acc = 0.f;
            for (int c = 0; c < C; c++) acc += sS[c] * Wm[k * C + c] * vs[c * 2 + h];
            fv[t] = acc;
        } else if (t < 84) {
            int h4 = t - 80, h = h4 & 1;
            const float* vs = (h4 < 2) ? vd1s : vd2s;
            float acc = 0.f;
            for (int c = 0; c < C; c++) acc += sSh[c] * vs[c * 2 + h];
            fv[t] = acc;
        }
        __syncthreads();
        int r = (bid - NB) * 256 + t;
        if (r < NR) {
            const float4* xp = (const float4*)(x + (size_t)r * DIN);
            float4 v0 = xp[0], v1 = xp[1], v2 = xp[2], v3 = xp[3], v4 = xp[4];
            float xv[20] = {v0.x, v0.y, v0.z, v0.w, v1.x, v1.y, v1.z, v1.w,
                            v2.x, v2.y, v2.z, v2.w, v3.x, v3.y, v3.z, v3.w,
                            v4.x, v4.y, v4.z, v4.w};
            float a0 = 0.f, a1 = 0.f, b0 = 0.f, b1 = 0.f;
            #pragma unroll
            for (int k = 0; k < DIN; k++) {
                float xvk = xv[k];
                a0 += xvk * fv[k * 4 + 0];
                a1 += xvk * fv[k * 4 + 1];
                b0 += xvk * fv[k * 4 + 2];
                b1 += xvk * fv[k * 4 + 3];
            }
            ((float2*)a_d)[r]  = make_float2(a0 + fv[80], a1 + fv[81]);
            ((float2*)advd)[r] = make_float2(b0 + fv[82], b1 + fv[83]);
        }
        return;
    }
    if (bid < NB + R0B + IB) {
        // ---- ingredient role ----
        float* u1s = (float*)sm;
        float* Ts  = u1s + 256;
        u1s[t] = stats[1200 + t];
        Ts[t] = stats[1712 + t];
        Ts[256 + t] = stats[1968 + t];
        __syncthreads();
        int r = t >> 3, cg = t & 7;
        int row = (bid - NB - R0B) * 32 + r;
        float as0 = 0.f, as1 = 0.f, p00 = 0.f, p01 = 0.f, p10 = 0.f, p11 = 0.f;
        if (row < NI) {
            const float* xp = ing_table + (size_t)ing_ids[row] * C + cg * 16;
            #pragma unroll
            for (int q = 0; q < 4; q++) {
                float4 v = ((const float4*)xp)[q];
                float xvv[4] = {v.x, v.y, v.z, v.w};
                #pragma unroll
                for (int jj = 0; jj < 4; jj++) {
                    int k = cg * 16 + q * 4 + jj;
                    float xx = xvv[jj];
                    as0 += xx * u1s[k * 2 + 0];
                    as1 += xx * u1s[k * 2 + 1];
                    p00 += xx * Ts[k * 4 + 0];
                    p01 += xx * Ts[k * 4 + 1];
                    p10 += xx * Ts[k * 4 + 2];
                    p11 += xx * Ts[k * 4 + 3];
                }
            }
        }
        #pragma unroll
        for (int m = 1; m <= 4; m <<= 1) {
            as0 += __shfl_xor(as0, m); as1 += __shfl_xor(as1, m);
            p00 += __shfl_xor(p00, m); p01 += __shfl_xor(p01, m);
            p10 += __shfl_xor(p10, m); p11 += __shfl_xor(p11, m);
        }
        if (cg == 0 && row < NI) {
            ((float2*)a_si)[row] = make_float2(as0, as1);
            float4 pv; pv.x = p00; pv.y = p01; pv.z = p10; pv.w = p11;
            ((float4*)psi)[row] = pv;
        }
        return;
    }
    // ---- user hs MFMA role ----
    u16* A = (u16*)sm;                       // 32*136*2 = 8704 B
    float* u2s = (float*)(sm + 8704);        // 1024 B
    u2s[t] = stats[1456 + t];
    int rowBase = (bid - NB - R0B - IB) * 32;
    int r = t >> 3, cg = t & 7;
    int row = rowBase + r;
    float xv[16];
    if (row < NU) {
        const float* xp = user_table + (size_t)user_ids[row] * C + cg * 16;
        #pragma unroll
        for (int q = 0; q < 4; q++) {
            float4 v = ((const float4*)xp)[q];
            xv[q * 4 + 0] = v.x; xv[q * 4 + 1] = v.y;
            xv[q * 4 + 2] = v.z; xv[q * 4 + 3] = v.w;
        }
    } else {
        #pragma unroll
        for (int q = 0; q < 16; q++) xv[q] = 0.f;
    }
    float ss = 0.f;
    #pragma unroll
    for (int q = 0; q < 16; q++) ss += xv[q] * xv[q];
    #pragma unroll
    for (int m = 1; m <= 4; m <<= 1) ss += __shfl_xor(ss, m);
    float nn = sqrtf(ss);
    float f = (nn > 1.f) ? 1.f / (nn + 1e-7f) : 1.f;
    float as0 = 0.f, as1 = 0.f;
    #pragma unroll
    for (int q = 0; q < 16; q++) {
        xv[q] *= f;
        int k = cg * 16 + q;
        as0 += xv[q] * u2s[k * 2 + 0];
        as1 += xv[q] * u2s[k * 2 + 1];
    }
    #pragma unroll
    for (int m = 1; m <= 4; m <<= 1) {
        as0 += __shfl_xor(as0, m); as1 += __shfl_xor(as1, m);
    }
    if (cg == 0 && row < NU) ((float2*)a_su)[row] = make_float2(as0, as1);
    {
        union { u16 h[16]; uint4 u4[2]; } pk;
        #pragma unroll
        for (int q = 0; q < 16; q++) pk.h[q] = f2bf_rne(xv[q]);
        uint4* dst = (uint4*)&A[r * 136 + cg * 16];
        dst[0] = pk.u4[0];
        dst[1] = pk.u4[1];
    }
    __syncthreads();
    int w = t >> 6, l = t & 63;
    int m15 = l & 15, q4 = l >> 4;
    bf16x8 afrag[2][4];
    #pragma unroll
    for (int mt = 0; mt < 2; mt++)
        #pragma unroll
        for (int kb = 0; kb < 4; kb++)
            afrag[mt][kb] = *(const bf16x8*)&A[(mt * 16 + m15) * 136 + kb * 32 + q4 * 8];
    f32x4 acc[2][4];
    #pragma unroll
    for (int mt = 0; mt < 2; mt++)
        #pragma unroll
        for (int i = 0; i < 4; i++) acc[mt][i] = (f32x4){0.f, 0.f, 0.f, 0.f};
    #pragma unroll
    for (int kb = 0; kb < 4; kb++) {
        #pragma unroll
        for (int i = 0; i < 4; i++) {
            int nt = w * 4 + i;
            bf16x8 bfrag = *(const bf16x8*)&wsp[((nt * 4 + kb) * 64 + l) * 8];
            acc[0][i] = __builtin_amdgcn_mfma_f32_16x16x32_bf16(afrag[0][kb], bfrag, acc[0][i], 0, 0, 0);
            acc[1][i] = __builtin_amdgcn_mfma_f32_16x16x32_bf16(afrag[1][kb], bfrag, acc[1][i], 0, 0, 0);
        }
    }
    #pragma unroll
    for (int mt = 0; mt < 2; mt++) {
        #pragma unroll
        for (int i = 0; i < 4; i++) {
            int col = (w * 4 + i) * 16 + m15;
            #pragma unroll
            for (int rr = 0; rr < 4; rr++) {
                int rw = rowBase + mt * 16 + q4 * 4 + rr;
                if (rw < NU) hs16[(size_t)rw * HC + col] = f2bf_rne(acc[mt][i][rr]);
            }
        }
    }
}

// ---------------- L3: fused GAT1 (psi) then GAT2 (R4 uint2 gather) ----------------
__global__ __launch_bounds__(256) void k_agg(const int* __restrict__ off2, const int* __restrict__ sorted,
    const float* __restrict__ a_si, const float* __restrict__ psi,
    const float* __restrict__ a_d1, const float* __restrict__ advd,
    const float* __restrict__ cb,
    const float* __restrict__ a_su, const u16* __restrict__ hs16,
    const float* __restrict__ bias, int NR, float* __restrict__ out)
{
    int wave = threadIdx.x >> 6, lane = threadIdx.x & 63;
    int d = blockIdx.x * 4 + wave;
    if (d >= NR) return;
    // ---------- phase 1: GAT1 psi aggregation ----------
    int beg = off2[2 * d], end = off2[2 * d + 1];
    float ad0 = a_d1[d * 2 + 0], ad1 = a_d1[d * 2 + 1];
    float w0s = 0.f, w1s = 0.f, a00 = 0.f, a01 = 0.f, a10 = 0.f, a11 = 0.f;
    for (int j = beg + lane; j < end; j += 64) {
        int s = sorted[j];
        float2 as = ((const float2*)a_si)[s];
        float e0 = as.x + ad0; e0 = (e0 >= 0.f) ? e0 : 0.2f * e0;
        float e1 = as.y + ad1; e1 = (e1 >= 0.f) ? e1 : 0.2f * e1;
        float x0 = __expf(e0), x1 = __expf(e1);
        float4 p = ((const float4*)psi)[s];
        w0s += x0; w1s += x1;
        a00 += x0 * p.x; a01 += x0 * p.y;
        a10 += x1 * p.z; a11 += x1 * p.w;
    }
    #pragma unroll
    for (int o = 1; o < 64; o <<= 1) {
        w0s += __shfl_xor(w0s, o); w1s += __shfl_xor(w1s, o);
        a00 += __shfl_xor(a00, o); a01 += __shfl_xor(a01, o);
        a10 += __shfl_xor(a10, o); a11 += __shfl_xor(a11, o);
    }
    float inv0g = 1.f / (w0s + 1e-16f), inv1g = 1.f / (w1s + 1e-16f);
    float r0 = advd[d * 2 + 0] + cb[0] + 0.5f * (a00 * inv0g + a10 * inv1g);
    float r1 = advd[d * 2 + 1] + cb[1] + 0.5f * (a01 * inv0g + a11 * inv1g);
    // ---------- phase 2: GAT2 hs16 row gather (R4 uint2 1-edge/step) ----------
    int i2 = NR + d;
    int beg2 = off2[2 * i2], end2 = off2[2 * i2 + 1];
    int head = lane >> 5;
    int q = lane & 31;
    u32 laneoff = (u32)(head * 256 + q * 8);
    int hsel = lane & 32;
    float adh = head ? r1 : r0;
    float wsum = 0.f;
    float acc0 = 0.f, acc1 = 0.f, acc2 = 0.f, acc3 = 0.f;
    const char* hbase = (const char*)hs16;

    for (int base = beg2; base < end2; base += 32) {
        int rem = end2 - base; if (rem > 32) rem = 32;
        int j = q; if (j >= rem) j = rem - 1;
        int sp = sorted[base + j];
        u32 boff = ((u32)sp) << 9;
        float asv = a_su[sp * 2 + head];
        float ee = asv + adh; ee = (ee >= 0.f) ? ee : 0.2f * ee;
        float wcomb = __expf(ee);
        int e = 0;
        for (; e + 4 <= rem; e += 4) {
            u32 b0 = __shfl(boff, e + 0), b1 = __shfl(boff, e + 1);
            u32 b2 = __shfl(boff, e + 2), b3 = __shfl(boff, e + 3);
            uint2 g0 = *(const uint2*)(hbase + (b0 + laneoff));
            uint2 g1 = *(const uint2*)(hbase + (b1 + laneoff));
            uint2 g2 = *(const uint2*)(hbase + (b2 + laneoff));
            uint2 g3 = *(const uint2*)(hbase + (b3 + laneoff));
            float W0 = __shfl(wcomb, hsel + e + 0);
            float W1 = __shfl(wcomb, hsel + e + 1);
            float W2 = __shfl(wcomb, hsel + e + 2);
            float W3 = __shfl(wcomb, hsel + e + 3);
            wsum += (W0 + W1) + (W2 + W3);
            acc0 += W0 * bfbits2f(g0.x & 0xFFFFu);
            acc1 += W0 * __uint_as_float(g0.x & 0xFFFF0000u);
            acc2 += W0 * bfbits2f(g0.y & 0xFFFFu);
            acc3 += W0 * __uint_as_float(g0.y & 0xFFFF0000u);
            acc0 += W1 * bfbits2f(g1.x & 0xFFFFu);
            acc1 += W1 * __uint_as_float(g1.x & 0xFFFF0000u);
            acc2 += W1 * bfbits2f(g1.y & 0xFFFFu);
            acc3 += W1 * __uint_as_float(g1.y & 0xFFFF0000u);
            acc0 += W2 * bfbits2f(g2.x & 0xFFFFu);
            acc1 += W2 * __uint_as_float(g2.x & 0xFFFF0000u);
            acc2 += W2 * bfbits2f(g2.y & 0xFFFFu);
            acc3 += W2 * __uint_as_float(g2.y & 0xFFFF0000u);
            acc0 += W3 * bfbits2f(g3.x & 0xFFFFu);
            acc1 += W3 * __uint_as_float(g3.x & 0xFFFF0000u);
            acc2 += W3 * bfbits2f(g3.y & 0xFFFFu);
            acc3 += W3 * __uint_as_float(g3.y & 0xFFFF0000u);
        }
        for (; e < rem; e++) {
            u32 b0 = __shfl(boff, e);
            float W = __shfl(wcomb, hsel + e);
            uint2 g = *(const uint2*)(hbase + (b0 + laneoff));
            wsum += W;
            acc0 += W * bfbits2f(g.x & 0xFFFFu);
            acc1 += W * __uint_as_float(g.x & 0xFFFF0000u);
            acc2 += W * bfbits2f(g.y & 0xFFFFu);
            acc3 += W * __uint_as_float(g.y & 0xFFFF0000u);
        }
    }
    float inv = 1.f / (wsum + 1e-16f);
    float v0 = acc0 * inv, v1 = acc1 * inv, v2 = acc2 * inv, v3 = acc3 * inv;
    v0 = 0.5f * (v0 + __shfl_xor(v0, 32));
    v1 = 0.5f * (v1 + __shfl_xor(v1, 32));
    v2 = 0.5f * (v2 + __shfl_xor(v2, 32));
    v3 = 0.5f * (v3 + __shfl_xor(v3, 32));
    if (lane < 32) {
        float4 bb = ((const float4*)bias)[q];
        float4 o;
        o.x = v0 + bb.x; o.y = v1 + bb.y; o.z = v2 + bb.z; o.w = v3 + bb.w;
        ((float4*)(out + (size_t)d * C))[q] = o;
    }
}

extern "C" void kernel_launch(void* const* d_in, const int* in_sizes, int n_in,
                              void* d_out, int out_size, void* d_ws, size_t ws_size,
                              hipStream_t stream) {
    const int*   user_ids       = (const int*)d_in[0];
    const int*   ingredient_ids = (const int*)d_in[1];
    const float* recipe_x       = (const float*)d_in[2];
    const int*   ing_src        = (const int*)d_in[3];
    const int*   ing_dst        = (const int*)d_in[4];
    const int*   ub_src         = (const int*)d_in[5];
    const int*   ub_dst         = (const int*)d_in[6];
    const float* user_table     = (const float*)d_in[7];
    const float* ing_table      = (const float*)d_in[8];
    const float* W_rl           = (const float*)d_in[9];
    const float* bn_gamma       = (const float*)d_in[11];
    const float* bn_beta        = (const float*)d_in[12];
    const float* g1_ws          = (const float*)d_in[13];
    const float* g1_wd          = (const float*)d_in[14];
    const float* g1_as          = (const float*)d_in[15];
    const float* g1_ad          = (const float*)d_in[16];
    const float* g1_b           = (const float*)d_in[17];
    const float* g2_ws          = (const float*)d_in[18];
    const float* g2_wd          = (const float*)d_in[19];
    const float* g2_as          = (const float*)d_in[20];
    const float* g2_ad          = (const float*)d_in[21];
    const float* g2_b           = (const float*)d_in[22];

    int NU = in_sizes[0];
    int NI = in_sizes[1];
    int NR = in_sizes[2] / DIN;
    int E1 = in_sizes[3];
    int E2 = in_sizes[5];
    int Nmax = (NI > NU) ? NI : NU;
    int L1 = (NI < NR) ? NI : NR;
    int L2 = (NU < NR) ? NU : NR;
    int Etot = E1 + L1 + E2 + L2;
    int n2 = 2 * NR;
    int NB = (n2 + 511) >> 9;

    char* w = (char*)d_ws;
    u16*   hs16  = (u16*)w;    w += (size_t)Nmax * HC * 2;
    float* a_si  = (float*)w;  w += (size_t)NI * 2 * 4;
    float* a_su  = (float*)w;  w += (size_t)NU * 2 * 4;
    float* psi   = (float*)w;  w += (size_t)NI * 4 * 4;
    float* a_d   = (float*)w;  w += (size_t)NR * 2 * 4;
    float* advd  = (float*)w;  w += (size_t)NR * 2 * 4;
    float* stats = (float*)w;  w += 2432 * 4;
    u32*   bucketFill = (u32*)w; w += MAXNB * 4;     // adjacent to stats: one memset
    u16*   wsp   = (u16*)w;    w += 32768 * 2;
    int*   off2  = (int*)w;    w += (size_t)(2 * n2) * 4;
    int*   sorted= (int*)w;    w += (size_t)NB * CAP * 4;
    u32*   pairs = (u32*)w;    w += (size_t)NB * CAP * 4;

    hipMemsetAsync(stats, 0, (2432 + MAXNB) * 4, stream);

    int SB  = (NR + 255) / 256;
    int A2B = (Etot + EB2 - 1) / EB2;
    // L1: BN stats ∥ kA2 bucket sort ∥ B-pack ∥ attention dots (+T,+cb)
    k_init<<<SB + A2B + 32 + 4, 256, 0, stream>>>(recipe_x, NR, stats, SB, A2B,
                                              ing_src, ing_dst, ub_src, ub_dst,
                                              E1, L1, E2, L2, NB,
                                              bucketFill, pairs, g2_ws, wsp,
                                              g1_wd, g1_ad, g2_wd, g2_ad,
                                              g1_ws, g1_as, g2_as, g1_b);
    // L2: kB fine sort ∥ r0f (inline fold+fv) ∥ ingredient psi ∥ user hs MFMA
    int R0B = (NR + 255) / 256;
    int IB  = (NI + 31) / 32;
    int HB  = (NU + 31) / 32;
    k_fin<<<NB + R0B + IB + HB, 256, 0, stream>>>(pairs, bucketFill, n2, NB, R0B, IB,
                                                  off2, sorted,
                                                  recipe_x, NR, stats,
                                                  W_rl, bn_gamma, bn_beta, 1.0f / NR,
                                                  a_d, advd,
                                                  ing_table, ingredient_ids, NI, a_si, psi,
                                                  user_table, user_ids, NU,
                                                  wsp, hs16, a_su);
    // L3: fused GAT1 + GAT2 aggregation
    k_agg<<<(NR + 3) / 4, 256, 0, stream>>>(off2, sorted, a_si, psi, a_d, advd,
                                            stats + 1188, a_su, hs16, g2_b, NR,
                                            (float*)d_out);
}

// Round 12
// 280.588 us; speedup vs baseline: 1.2799x; 1.0410x over previous
//
#include <hip/hip_runtime.h>
#include <hip/hip_bf16.h>
#include <math.h>

#define DIN 20
#define C 128
#define HC 256
#define EB2 2048
#define MAXNB 400
#define CAP 8192
#define CAPSH 13

typedef unsigned short u16;
typedef unsigned int u32;
typedef unsigned long long u64;
typedef __bf16 bf16x8 __attribute__((ext_vector_type(8)));
typedef float f32x4 __attribute__((ext_vector_type(4)));

__device__ __forceinline__ float bfbits2f(unsigned int lo16) {
    return __uint_as_float(lo16 << 16);
}
__device__ __forceinline__ u16 f2bf_rne(float f) {
    unsigned int b = __float_as_uint(f);
    return (u16)((b + 0x7FFFu + ((b >> 16) & 1u)) >> 16);
}

// exclusive scan of cnt[0..511] -> off[0..511]; wave-shuffle scan, 2 barriers
__device__ __forceinline__ void scan512f(u32* cnt, u32* off, u32* wsum4) {
    int t = threadIdx.x;
    int l = t & 63, w = t >> 6;
    u32 a = cnt[2 * t], b = cnt[2 * t + 1];
    u32 s = a + b;
    u32 isc = s;
    #pragma unroll
    for (int o = 1; o < 64; o <<= 1) {
        u32 n = __shfl_up(isc, o);
        if (l >= o) isc += n;
    }
    if (l == 63) wsum4[w] = isc;
    __syncthreads();
    u32 pre = 0;
    if (w > 0) pre += wsum4[0];
    if (w > 1) pre += wsum4[1];
    if (w > 2) pre += wsum4[2];
    u32 excl = pre + isc - s;
    off[2 * t] = excl;
    off[2 * t + 1] = excl + a;
    __syncthreads();
}

__device__ __forceinline__ void edge_at(int i, const int* s1, const int* d1,
    const int* s2, const int* d2, int E1, int T1, int E2, int NR,
    int& s, int& key)
{
    if (i < T1) {
        if (i < E1) { s = s1[i]; key = d1[i]; }
        else        { s = i - E1; key = i - E1; }
    } else {
        int k = i - T1;
        if (k < E2) { s = s2[k]; key = NR + d2[k]; }
        else        { s = k - E2; key = NR + (k - E2); }
    }
}

// ---- L1: BN stats ∥ kA2 bucket-sort (u32 pairs) ∥ B-pack ∥ dots (+T,+cb) --------
// blocks [0,SB): BN; [SB,+A2B): kA2; [+32): pack; [+4): dots (dr1 also does T,cb)
__global__ __launch_bounds__(256) void k_init(const float* __restrict__ x, int NR,
    float* __restrict__ stats, int SB, int A2B,
    const int* __restrict__ src1, const int* __restrict__ dst1,
    const int* __restrict__ src2, const int* __restrict__ dst2,
    int E1, int L1, int E2, int L2, int NB,
    u32* __restrict__ bucketFill, u32* __restrict__ pairs,
    const float* __restrict__ g2_ws, u16* __restrict__ wsp,
    const float* __restrict__ g1_wd, const float* __restrict__ g1_ad,
    const float* __restrict__ g2_wd, const float* __restrict__ g2_ad,
    const float* __restrict__ g1_ws, const float* __restrict__ g1_as,
    const float* __restrict__ g2_as, const float* __restrict__ g1b)
{
    __shared__ __align__(16) char sm[40528];
    int t = threadIdx.x;
    int bid = blockIdx.x;
    if (bid < SB) {
        // ---- BN stats role (vectorized row load) ----
        float (*L)[DIN] = (float(*)[DIN])sm;
        int r = bid * 256 + t;
        if (r < NR) {
            const float4* xp = (const float4*)(x + (size_t)r * DIN);
            float4 v0 = xp[0], v1 = xp[1], v2 = xp[2], v3 = xp[3], v4 = xp[4];
            L[t][0] = v0.x; L[t][1] = v0.y; L[t][2] = v0.z; L[t][3] = v0.w;
            L[t][4] = v1.x; L[t][5] = v1.y; L[t][6] = v1.z; L[t][7] = v1.w;
            L[t][8] = v2.x; L[t][9] = v2.y; L[t][10] = v2.z; L[t][11] = v2.w;
            L[t][12] = v3.x; L[t][13] = v3.y; L[t][14] = v3.z; L[t][15] = v3.w;
            L[t][16] = v4.x; L[t][17] = v4.y; L[t][18] = v4.z; L[t][19] = v4.w;
        } else {
            #pragma unroll
            for (int k = 0; k < DIN; k++) L[t][k] = 0.f;
        }
        __syncthreads();
        if (t < 210) {
            int p = 0, q = t;
            while (q >= DIN - p) { q -= (DIN - p); p++; }
            q += p;
            float acc = 0.f;
            for (int rr = 0; rr < 256; rr++) acc += L[rr][p] * L[rr][q];
            atomicAdd(&stats[p * DIN + q], acc);
            if (p != q) atomicAdd(&stats[q * DIN + p], acc);
        } else if (t < 230) {
            int k = t - 210;
            float acc = 0.f;
            for (int rr = 0; rr < 256; rr++) acc += L[rr][k];
            atomicAdd(&stats[400 + k], acc);
        }
        return;
    }
    if (bid < SB + A2B) {
        // ---- kA2 role: LDS counting sort by bucket; u32 packed global writes ----
        u64* ldsE = (u64*)sm;                    // 2048*8 = 16384
        u64* ldsS = ldsE + EB2;                  // 16384
        u32* cntA = (u32*)(ldsS + EB2);          // 2048
        u32* cntB = cntA + 512;                  // 2048
        u32* offL = cntB + 512;                  // 2048
        u32* wsum4 = offL + 512;                 // 16
        u32* gbase = wsum4 + 4;                  // 1600
        for (int i = t; i < 512; i += 256) { cntA[i] = 0; cntB[i] = 0; }
        __syncthreads();
        int T1 = E1 + L1, T = T1 + E2 + L2;
        int base = (bid - SB) * EB2;
        int nE = T - base; if (nE > EB2) nE = EB2;
        for (int j = t; j < nE; j += 256) {
            int s, key;
            edge_at(base + j, src1, dst1, src2, dst2, E1, T1, E2, NR, s, key);
            ldsE[j] = ((u64)(u32)key << 32) | (u32)s;
            atomicAdd(&cntA[key >> 9], 1u);
        }
        __syncthreads();
        scan512f(cntA, offL, wsum4);
        for (int b = t; b < NB; b += 256) {
            u32 c = cntA[b];
            gbase[b] = c ? (((u32)b << CAPSH) + atomicAdd(&bucketFill[b], c)) : 0u;
        }
        __syncthreads();
        for (int j = t; j < nE; j += 256) {
            u64 e = ldsE[j];
            u32 b = ((u32)(e >> 32)) >> 9;
            u32 r = atomicAdd(&cntB[b], 1u);
            ldsS[offL[b] + r] = e;
        }
        __syncthreads();
        for (int j = t; j < nE; j += 256) {
            u64 e = ldsS[j];
            u32 key = (u32)(e >> 32);
            u32 b = key >> 9;
            // pack: fine(9b) << 17 | src(17b) -- src < 2^17 for this problem
            pairs[gbase[b] + ((u32)j - offL[b])] = ((key & 511u) << 17) | (u32)e;
        }
        return;
    }
    if (bid < SB + A2B + 32) {
        // ---- B-pack role (32 blocks) ----
        int idx0 = ((bid - SB - A2B) * 256 + t) * 4;
        #pragma unroll
        for (int i = 0; i < 4; i++) {
            int flat = idx0 + i;           // [nt(16)][kb(4)][lane(64)][j(8)]
            int j = flat & 7;
            int lane = (flat >> 3) & 63;
            int kb = (flat >> 9) & 3;
            int nt = flat >> 11;
            int k = kb * 32 + (lane >> 4) * 8 + j;
            int n = nt * 16 + (lane & 15);
            wsp[flat] = f2bf_rne(g2_ws[k * HC + n]);
        }
        return;
    }
    // ---- attention dot role (4 blocks) ----
    // dr0: vd1=g1_wd·g1_ad  dr1: vd2=g2_wd·g2_ad (+T,+cb)  dr2: u1  dr3: u2
    int dr = bid - SB - A2B - 32;
    const float* wm = (dr == 0) ? g1_wd : (dr == 1) ? g2_wd : (dr == 2) ? g1_ws : g2_ws;
    const float* am = (dr == 0) ? g1_ad : (dr == 1) ? g2_ad : (dr == 2) ? g1_as : g2_as;
    int obase = (dr == 0) ? 676 : (dr == 1) ? 932 : (dr == 2) ? 1200 : 1456;
    float* vd2l = (float*)sm;
    float acc = 0.f;
    {
        int k = t >> 1, h = t & 1;
        const float4* wp = (const float4*)(wm + k * HC + h * C);
        const float4* ap = (const float4*)(am + h * C);
        #pragma unroll 4
        for (int q = 0; q < 32; q++) {
            float4 xv = wp[q], yv = ap[q];
            acc += xv.x * yv.x + xv.y * yv.y + xv.z * yv.z + xv.w * yv.w;
        }
        stats[obase + t] = acc;
    }
    if (dr == 1) {
        vd2l[t] = acc;
        __syncthreads();
        // T[k*4+h*2+h'] = sum_c g1_ws[k][h*C+c] * vd2[c*2+h']
        int k = t >> 1, h = t & 1;
        const float4* ws1p = (const float4*)(g1_ws + k * HC + h * C);
        float t0 = 0.f, t1 = 0.f;
        #pragma unroll 4
        for (int q = 0; q < 32; q++) {
            float4 wv = ws1p[q];
            int c = q * 4;
            t0 += wv.x * vd2l[(c + 0) * 2 + 0] + wv.y * vd2l[(c + 1) * 2 + 0]
                + wv.z * vd2l[(c + 2) * 2 + 0] + wv.w * vd2l[(c + 3) * 2 + 0];
            t1 += wv.x * vd2l[(c + 0) * 2 + 1] + wv.y * vd2l[(c + 1) * 2 + 1]
                + wv.z * vd2l[(c + 2) * 2 + 1] + wv.w * vd2l[(c + 3) * 2 + 1];
        }
        stats[1712 + t * 2 + 0] = t0;
        stats[1712 + t * 2 + 1] = t1;
        if (t < 2) {
            float cb = 0.f;
            for (int k2 = 0; k2 < C; k2++) cb += g1b[k2] * vd2l[k2 * 2 + t];
            stats[1188 + t] = cb;
        }
    }
}

// ---------------- L2: kB fine sort ∥ r0f (inline BN fold+fv) ∥ ing ∥ user hs ------
// blocks [0,NB): kB -> off2/sorted; [NB,+R0B): r0f; [+IB): ing; [+HB): hs
__global__ __launch_bounds__(256) void k_fin(const u32* __restrict__ pairs,
    const u32* __restrict__ bucketFill, int n2, int NB, int R0B, int IB,
    int* __restrict__ off2, int* __restrict__ sorted,
    const float* __restrict__ x, int NR, const float* __restrict__ stats,
    const float* __restrict__ W, const float* __restrict__ gamma,
    const float* __restrict__ beta, float invN,
    float* __restrict__ a_d, float* __restrict__ advd,
    const float* __restrict__ ing_table, const int* __restrict__ ing_ids, int NI,
    float* __restrict__ a_si, float* __restrict__ psi,
    const float* __restrict__ user_table, const int* __restrict__ user_ids, int NU,
    const u16* __restrict__ wsp, u16* __restrict__ hs16, float* __restrict__ a_su)
{
    __shared__ __align__(16) char sm[30736];
    int t = threadIdx.x;
    int bid = blockIdx.x;
    if (bid < NB) {
        u32* cntA = (u32*)sm;          // 2048
        u32* cntB = cntA + 512;        // 2048
        u32* offL = cntB + 512;        // 2048
        u32* wsum4 = offL + 512;       // 16
        u32* ldsS = wsum4 + 4;         // 6144*4 = 24576
        int b = bid;
        u32 beg = (u32)b << CAPSH;
        u32 fill = bucketFill[b];
        u32 end = beg + fill;
        int dstBase = b << 9;
        for (int i = t; i < 512; i += 256) { cntA[i] = 0; cntB[i] = 0; }
        __syncthreads();
        for (u32 j = beg + t; j < end; j += 256) {
            u32 fine = pairs[j] >> 17;
            atomicAdd(&cntA[fine], 1u);
        }
        __syncthreads();
        scan512f(cntA, offL, wsum4);
        for (int d = t; d < 512; d += 256) {
            int gk = dstBase + d;
            if (gk < n2) {
                int s0 = (int)(beg + offL[d]);
                off2[2 * gk] = s0;
                off2[2 * gk + 1] = s0 + (int)cntA[d];
            }
        }
        bool fast = fill <= 6144u;
        __syncthreads();
        for (u32 j = beg + t; j < end; j += 256) {
            u32 p = pairs[j];
            u32 d = p >> 17;
            u32 r = atomicAdd(&cntB[d], 1u);
            u32 pos = offL[d] + r;
            u32 src = p & 0x1FFFFu;
            if (fast) ldsS[pos] = src;
            else sorted[beg + pos] = (int)src;
        }
        __syncthreads();
        if (fast) {
            for (u32 j = t; j < fill; j += 256) sorted[beg + j] = (int)ldsS[j];
        }
        return;
    }
    if (bid < NB + R0B) {
        // ---- r0f GEMV role with per-block inline BN fold + fv ----
        float* Sm   = (float*)sm;          // 420
        float* Wm   = Sm + 420;            // 2560
        float* vd1s = Wm + 2560;           // 256
        float* vd2s = vd1s + 256;          // 256
        float* sS   = vd2s + 256;          // 128
        float* sSh  = sS + 128;            // 128
        float* fv   = sSh + 128;           // 84  (total 4092 floats = 16368 B)
        for (int i = t; i < 420; i += 256) Sm[i] = stats[i];
        for (int i = t; i < DIN * C; i += 256) Wm[i] = W[i];
        vd1s[t] = stats[676 + t];
        vd2s[t] = stats[932 + t];
        __syncthreads();
        if (t < C) {
            float w[DIN];
            #pragma unroll
            for (int k = 0; k < DIN; k++) w[k] = Wm[k * C + t];
            float mb = 0.f;
            #pragma unroll
            for (int k = 0; k < DIN; k++) mb += Sm[400 + k] * invN * w[k];
            float e2 = 0.f;
            for (int p = 0; p < DIN; p++) {
                float acc2 = 0.f;
                #pragma unroll
                for (int q = 0; q < DIN; q++) acc2 += Sm[p * DIN + q] * w[q];
                e2 += w[p] * acc2;
            }
            e2 *= invN;
            float var = e2 - mb * mb;
            float s = gamma[t] * rsqrtf(var + 1e-5f);
            sS[t] = s;
            sSh[t] = beta[t] - s * mb;   // b_rl cancels inside BN
        }
        __syncthreads();
        if (t < 80) {
            int k = t >> 2, h4 = t & 3, h = h4 & 1;
            const float* vs = (h4 < 2) ? vd1s : vd2s;
            float acc = 0.f;
            for (int c = 0; c < C; c++) acc += sS[c] * Wm[k * C + c] * vs[c * 2 + h];
            fv[t] = acc;
        } else if (t < 84) {
            int h4 = t - 80, h = h4 & 1;
            const float* vs = (h4 < 2) ? vd1s : vd2s;
            float acc = 0.f;
            for (int c = 0; c < C; c++) acc += sSh[c] * vs[c * 2 + h];
            fv[t] = acc;
        }
        __syncthreads();
        int r = (bid - NB) * 256 + t;
        if (r < NR) {
            const float4* xp = (const float4*)(x + (size_t)r * DIN);
            float4 v0 = xp[0], v1 = xp[1], v2 = xp[2], v3 = xp[3], v4 = xp[4];
            float xv[20] = {v0.x, v0.y, v0.z, v0.w, v1.x, v1.y, v1.z, v1.w,
                            v2.x, v2.y, v2.z, v2.w, v3.x, v3.y, v3.z, v3.w,
                            v4.x, v4.y, v4.z, v4.w};
            float a0 = 0.f, a1 = 0.f, b0 = 0.f, b1 = 0.f;
            #pragma unroll
            for (int k = 0; k < DIN; k++) {
                float xvk = xv[k];
                a0 += xvk * fv[k * 4 + 0];
                a1 += xvk * fv[k * 4 + 1];
                b0 += xvk * fv[k * 4 + 2];
                b1 += xvk * fv[k * 4 + 3];
            }
            ((float2*)a_d)[r]  = make_float2(a0 + fv[80], a1 + fv[81]);
            ((float2*)advd)[r] = make_float2(b0 + fv[82], b1 + fv[83]);
        }
        return;
    }
    if (bid < NB + R0B + IB) {
        // ---- ingredient role ----
        float* u1s = (float*)sm;
        float* Ts  = u1s + 256;
        u1s[t] = stats[1200 + t];
        Ts[t] = stats[1712 + t];
        Ts[256 + t] = stats[1968 + t];
        __syncthreads();
        int r = t >> 3, cg = t & 7;
        int row = (bid - NB - R0B) * 32 + r;
        float as0 = 0.f, as1 = 0.f, p00 = 0.f, p01 = 0.f, p10 = 0.f, p11 = 0.f;
        if (row < NI) {
            const float* xp = ing_table + (size_t)ing_ids[row] * C + cg * 16;
            #pragma unroll
            for (int q = 0; q < 4; q++) {
                float4 v = ((const float4*)xp)[q];
                float xvv[4] = {v.x, v.y, v.z, v.w};
                #pragma unroll
                for (int jj = 0; jj < 4; jj++) {
                    int k = cg * 16 + q * 4 + jj;
                    float xx = xvv[jj];
                    as0 += xx * u1s[k * 2 + 0];
                    as1 += xx * u1s[k * 2 + 1];
                    p00 += xx * Ts[k * 4 + 0];
                    p01 += xx * Ts[k * 4 + 1];
                    p10 += xx * Ts[k * 4 + 2];
                    p11 += xx * Ts[k * 4 + 3];
                }
            }
        }
        #pragma unroll
        for (int m = 1; m <= 4; m <<= 1) {
            as0 += __shfl_xor(as0, m); as1 += __shfl_xor(as1, m);
            p00 += __shfl_xor(p00, m); p01 += __shfl_xor(p01, m);
            p10 += __shfl_xor(p10, m); p11 += __shfl_xor(p11, m);
        }
        if (cg == 0 && row < NI) {
            ((float2*)a_si)[row] = make_float2(as0, as1);
            float4 pv; pv.x = p00; pv.y = p01; pv.z = p10; pv.w = p11;
            ((float4*)psi)[row] = pv;
        }
        return;
    }
    // ---- user hs MFMA role ----
    u16* A = (u16*)sm;                       // 32*136*2 = 8704 B
    float* u2s = (float*)(sm + 8704);        // 1024 B
    u2s[t] = stats[1456 + t];
    int rowBase = (bid - NB - R0B - IB) * 32;
    int r = t >> 3, cg = t & 7;
    int row = rowBase + r;
    float xv[16];
    if (row < NU) {
        const float* xp = user_table + (size_t)user_ids[row] * C + cg * 16;
        #pragma unroll
        for (int q = 0; q < 4; q++) {
            float4 v = ((const float4*)xp)[q];
            xv[q * 4 + 0] = v.x; xv[q * 4 + 1] = v.y;
            xv[q * 4 + 2] = v.z; xv[q * 4 + 3] = v.w;
        }
    } else {
        #pragma unroll
        for (int q = 0; q < 16; q++) xv[q] = 0.f;
    }
    float ss = 0.f;
    #pragma unroll
    for (int q = 0; q < 16; q++) ss += xv[q] * xv[q];
    #pragma unroll
    for (int m = 1; m <= 4; m <<= 1) ss += __shfl_xor(ss, m);
    float nn = sqrtf(ss);
    float f = (nn > 1.f) ? 1.f / (nn + 1e-7f) : 1.f;
    float as0 = 0.f, as1 = 0.f;
    #pragma unroll
    for (int q = 0; q < 16; q++) {
        xv[q] *= f;
        int k = cg * 16 + q;
        as0 += xv[q] * u2s[k * 2 + 0];
        as1 += xv[q] * u2s[k * 2 + 1];
    }
    #pragma unroll
    for (int m = 1; m <= 4; m <<= 1) {
        as0 += __shfl_xor(as0, m); as1 += __shfl_xor(as1, m);
    }
    if (cg == 0 && row < NU) ((float2*)a_su)[row] = make_float2(as0, as1);
    {
        union { u16 h[16]; uint4 u4[2]; } pk;
        #pragma unroll
        for (int q = 0; q < 16; q++) pk.h[q] = f2bf_rne(xv[q]);
        uint4* dst = (uint4*)&A[r * 136 + cg * 16];
        dst[0] = pk.u4[0];
        dst[1] = pk.u4[1];
    }
    __syncthreads();
    int w = t >> 6, l = t & 63;
    int m15 = l & 15, q4 = l >> 4;
    bf16x8 afrag[2][4];
    #pragma unroll
    for (int mt = 0; mt < 2; mt++)
        #pragma unroll
        for (int kb = 0; kb < 4; kb++)
            afrag[mt][kb] = *(const bf16x8*)&A[(mt * 16 + m15) * 136 + kb * 32 + q4 * 8];
    f32x4 acc[2][4];
    #pragma unroll
    for (int mt = 0; mt < 2; mt++)
        #pragma unroll
        for (int i = 0; i < 4; i++) acc[mt][i] = (f32x4){0.f, 0.f, 0.f, 0.f};
    #pragma unroll
    for (int kb = 0; kb < 4; kb++) {
        #pragma unroll
        for (int i = 0; i < 4; i++) {
            int nt = w * 4 + i;
            bf16x8 bfrag = *(const bf16x8*)&wsp[((nt * 4 + kb) * 64 + l) * 8];
            acc[0][i] = __builtin_amdgcn_mfma_f32_16x16x32_bf16(afrag[0][kb], bfrag, acc[0][i], 0, 0, 0);
            acc[1][i] = __builtin_amdgcn_mfma_f32_16x16x32_bf16(afrag[1][kb], bfrag, acc[1][i], 0, 0, 0);
        }
    }
    #pragma unroll
    for (int mt = 0; mt < 2; mt++) {
        #pragma unroll
        for (int i = 0; i < 4; i++) {
            int col = (w * 4 + i) * 16 + m15;
            #pragma unroll
            for (int rr = 0; rr < 4; rr++) {
                int rw = rowBase + mt * 16 + q4 * 4 + rr;
                if (rw < NU) hs16[(size_t)rw * HC + col] = f2bf_rne(acc[mt][i][rr]);
            }
        }
    }
}

// ---------------- L3: fused GAT1+GAT2, TWO dsts per wave (half-wave each) ---------
// Half-wave (32 lanes) owns one dst. Phase 2: 32 lanes x uint4 (16B) = 512B row;
// lane holds 8 channels of head (lg>>4); wsum needs no reduce; head-mean = xor16.
// NOTE: all __shfl executed UNCONDITIONALLY (divergent-shfl reads from
// EXEC-masked source lanes are undefined on CDNA -- R11 bug).
__global__ __launch_bounds__(256) void k_agg(const int* __restrict__ off2, const int* __restrict__ sorted,
    const float* __restrict__ a_si, const float* __restrict__ psi,
    const float* __restrict__ a_d1, const float* __restrict__ advd,
    const float* __restrict__ cb,
    const float* __restrict__ a_su, const u16* __restrict__ hs16,
    const float* __restrict__ bias, int NR, float* __restrict__ out)
{
    int wave = threadIdx.x >> 6, lane = threadIdx.x & 63;
    int g = lane >> 5, lg = lane & 31;
    int d = blockIdx.x * 8 + wave * 2 + g;
    bool dv = d < NR;
    int dd = dv ? d : NR - 1;
    int sbase = lane & 32;                 // shuffle base of own half
    // ---------- phase 1: GAT1 psi aggregation (per half-wave) ----------
    int beg = off2[2 * dd];
    int end = dv ? off2[2 * dd + 1] : beg;
    float ad0 = a_d1[dd * 2 + 0], ad1 = a_d1[dd * 2 + 1];
    float w0s = 0.f, w1s = 0.f, a00 = 0.f, a01 = 0.f, a10 = 0.f, a11 = 0.f;
    for (int j = beg + lg; j < end; j += 32) {
        int s = sorted[j];
        float2 as = ((const float2*)a_si)[s];
        float e0 = as.x + ad0; e0 = (e0 >= 0.f) ? e0 : 0.2f * e0;
        float e1 = as.y + ad1; e1 = (e1 >= 0.f) ? e1 : 0.2f * e1;
        float x0 = __expf(e0), x1 = __expf(e1);
        float4 p = ((const float4*)psi)[s];
        w0s += x0; w1s += x1;
        a00 += x0 * p.x; a01 += x0 * p.y;
        a10 += x1 * p.z; a11 += x1 * p.w;
    }
    #pragma unroll
    for (int o = 1; o < 32; o <<= 1) {     // stays within own 32-lane half
        w0s += __shfl_xor(w0s, o); w1s += __shfl_xor(w1s, o);
        a00 += __shfl_xor(a00, o); a01 += __shfl_xor(a01, o);
        a10 += __shfl_xor(a10, o); a11 += __shfl_xor(a11, o);
    }
    float inv0g = 1.f / (w0s + 1e-16f), inv1g = 1.f / (w1s + 1e-16f);
    float r0 = advd[dd * 2 + 0] + cb[0] + 0.5f * (a00 * inv0g + a10 * inv1g);
    float r1 = advd[dd * 2 + 1] + cb[1] + 0.5f * (a01 * inv0g + a11 * inv1g);
    // ---------- phase 2: GAT2 hs16 row gather (uint4, per half-wave) ----------
    int i2 = NR + dd;
    int beg2 = off2[2 * i2];
    int end2 = dv ? off2[2 * i2 + 1] : beg2;
    int head = lg >> 4, hq = lg & 15;
    u32 laneoff = (u32)(head * 256 + hq * 16);
    float wsum = 0.f;
    float acc[8];
    #pragma unroll
    for (int k = 0; k < 8; k++) acc[k] = 0.f;
    const char* hbase = (const char*)hs16;

    for (int base = beg2; base < end2; base += 32) {
        int rem = end2 - base; if (rem > 32) rem = 32;
        int j = lg; if (j >= rem) j = rem - 1;
        int sp = sorted[base + j];
        u32 boff = ((u32)sp) << 9;
        float2 av = ((const float2*)a_su)[sp];
        float e0 = av.x + r0; e0 = (e0 >= 0.f) ? e0 : 0.2f * e0;
        float e1 = av.y + r1; e1 = (e1 >= 0.f) ? e1 : 0.2f * e1;
        float w0 = __expf(e0), w1 = __expf(e1);
        for (int e = 0; e < rem; e++) {
            int srcl = sbase + e;
            u32 bo = __shfl(boff, srcl);
            float W0 = __shfl(w0, srcl);    // both shuffles unconditional:
            float W1 = __shfl(w1, srcl);    // all source lanes active
            float W = head ? W1 : W0;       // select AFTER the shuffles
            uint4 gg = *(const uint4*)(hbase + (bo + laneoff));
            wsum += W;
            acc[0] += W * bfbits2f(gg.x & 0xFFFFu);
            acc[1] += W * __uint_as_float(gg.x & 0xFFFF0000u);
            acc[2] += W * bfbits2f(gg.y & 0xFFFFu);
            acc[3] += W * __uint_as_float(gg.y & 0xFFFF0000u);
            acc[4] += W * bfbits2f(gg.z & 0xFFFFu);
            acc[5] += W * __uint_as_float(gg.z & 0xFFFF0000u);
            acc[6] += W * bfbits2f(gg.w & 0xFFFFu);
            acc[7] += W * __uint_as_float(gg.w & 0xFFFF0000u);
        }
    }
    float inv = 1.f / (wsum + 1e-16f);
    // head mean: lane lg and lg^16 hold the two heads, same channels
    #pragma unroll
    for (int k = 0; k < 8; k++) {
        float v = acc[k] * inv;
        acc[k] = 0.5f * (v + __shfl_xor(v, 16));
    }
    if (dv && head == 0) {
        const float4* b4 = (const float4*)bias;
        float4 bb0 = b4[hq * 2], bb1 = b4[hq * 2 + 1];
        float4 o0, o1;
        o0.x = acc[0] + bb0.x; o0.y = acc[1] + bb0.y;
        o0.z = acc[2] + bb0.z; o0.w = acc[3] + bb0.w;
        o1.x = acc[4] + bb1.x; o1.y = acc[5] + bb1.y;
        o1.z = acc[6] + bb1.z; o1.w = acc[7] + bb1.w;
        float4* op = (float4*)(out + (size_t)d * C + hq * 8);
        op[0] = o0; op[1] = o1;
    }
}

extern "C" void kernel_launch(void* const* d_in, const int* in_sizes, int n_in,
                              void* d_out, int out_size, void* d_ws, size_t ws_size,
                              hipStream_t stream) {
    const int*   user_ids       = (const int*)d_in[0];
    const int*   ingredient_ids = (const int*)d_in[1];
    const float* recipe_x       = (const float*)d_in[2];
    const int*   ing_src        = (const int*)d_in[3];
    const int*   ing_dst        = (const int*)d_in[4];
    const int*   ub_src         = (const int*)d_in[5];
    const int*   ub_dst         = (const int*)d_in[6];
    const float* user_table     = (const float*)d_in[7];
    const float* ing_table      = (const float*)d_in[8];
    const float* W_rl           = (const float*)d_in[9];
    const float* bn_gamma       = (const float*)d_in[11];
    const float* bn_beta        = (const float*)d_in[12];
    const float* g1_ws          = (const float*)d_in[13];
    const float* g1_wd          = (const float*)d_in[14];
    const float* g1_as          = (const float*)d_in[15];
    const float* g1_ad          = (const float*)d_in[16];
    const float* g1_b           = (const float*)d_in[17];
    const float* g2_ws          = (const float*)d_in[18];
    const float* g2_wd          = (const float*)d_in[19];
    const float* g2_as          = (const float*)d_in[20];
    const float* g2_ad          = (const float*)d_in[21];
    const float* g2_b           = (const float*)d_in[22];

    int NU = in_sizes[0];
    int NI = in_sizes[1];
    int NR = in_sizes[2] / DIN;
    int E1 = in_sizes[3];
    int E2 = in_sizes[5];
    int Nmax = (NI > NU) ? NI : NU;
    int L1 = (NI < NR) ? NI : NR;
    int L2 = (NU < NR) ? NU : NR;
    int Etot = E1 + L1 + E2 + L2;
    int n2 = 2 * NR;
    int NB = (n2 + 511) >> 9;

    char* w = (char*)d_ws;
    u16*   hs16  = (u16*)w;    w += (size_t)Nmax * HC * 2;
    float* a_si  = (float*)w;  w += (size_t)NI * 2 * 4;
    float* a_su  = (float*)w;  w += (size_t)NU * 2 * 4;
    float* psi   = (float*)w;  w += (size_t)NI * 4 * 4;
    float* a_d   = (float*)w;  w += (size_t)NR * 2 * 4;
    float* advd  = (float*)w;  w += (size_t)NR * 2 * 4;
    float* stats = (float*)w;  w += 2432 * 4;
    u32*   bucketFill = (u32*)w; w += MAXNB * 4;     // adjacent to stats: one memset
    u16*   wsp   = (u16*)w;    w += 32768 * 2;
    int*   off2  = (int*)w;    w += (size_t)(2 * n2) * 4;
    int*   sorted= (int*)w;    w += (size_t)NB * CAP * 4;
    u32*   pairs = (u32*)w;    w += (size_t)NB * CAP * 4;

    hipMemsetAsync(stats, 0, (2432 + MAXNB) * 4, stream);

    int SB  = (NR + 255) / 256;
    int A2B = (Etot + EB2 - 1) / EB2;
    // L1: BN stats ∥ kA2 bucket sort ∥ B-pack ∥ attention dots (+T,+cb)
    k_init<<<SB + A2B + 32 + 4, 256, 0, stream>>>(recipe_x, NR, stats, SB, A2B,
                                              ing_src, ing_dst, ub_src, ub_dst,
                                              E1, L1, E2, L2, NB,
                                              bucketFill, pairs, g2_ws, wsp,
                                              g1_wd, g1_ad, g2_wd, g2_ad,
                                              g1_ws, g1_as, g2_as, g1_b);
    // L2: kB fine sort ∥ r0f (inline fold+fv) ∥ ingredient psi ∥ user hs MFMA
    int R0B = (NR + 255) / 256;
    int IB  = (NI + 31) / 32;
    int HB  = (NU + 31) / 32;
    k_fin<<<NB + R0B + IB + HB, 256, 0, stream>>>(pairs, bucketFill, n2, NB, R0B, IB,
                                                  off2, sorted,
                                                  recipe_x, NR, stats,
                                                  W_rl, bn_gamma, bn_beta, 1.0f / NR,
                                                  a_d, advd,
                                                  ing_table, ingredient_ids, NI, a_si, psi,
                                                  user_table, user_ids, NU,
                                                  wsp, hs16, a_su);
    // L3: fused GAT1 + GAT2 aggregation, 2 dsts per wave
    k_agg<<<(NR + 7) / 8, 256, 0, stream>>>(off2, sorted, a_si, psi, a_d, advd,
                                            stats + 1188, a_su, hs16, g2_b, NR,
                                            (float*)d_out);
}